// Round 5
// baseline (38393.613 us; speedup 1.0000x reference)
//
#include <hip/hip_runtime.h>

// ============================================================================
// AgnisV5: sequential recurrence (4-phase persistent kernel) + deferred
//          batched lm_head GEMM (bf16 MFMA).
//
// Round-5 change: 32-WG RECURRENCE (was 256). R2/R3 evidence: exchange cost
// scales with (consumers x payload) on the sc1 path (~460GB/s effective);
// per-step traffic 18MB -> ~1.8MB by cutting consumers 8x. Weight slices no
// longer fit in LDS -> read from GLOBAL (transposed, k-contiguous, coalesced;
// ~886KB/WG/step, L2-resident: 4 WGs/XCD x 886KB = 3.5MB < 4MB XCD L2).
// Transport: UNCHANGED R3 primitives (__hip_atomic relaxed agent-scope u64,
// 3xbf16 payload + 16-bit step tag, self-validating; no fences, no barriers,
// no cache-bit asm - R4's hand-rolled sc0/XCC_ID scheme hung). Each WG runs
// the proven R3 phase bodies 8x (virtual-WG loop vg); word layouts identical.
// P4 emits fused pre-LN slice sigma(gv)*(cf+0.4tf)+(1-sigma)*emb (tf stays
// WG-local in LDS), so h-phase gathers 4 words/thread instead of 12.
// ============================================================================

typedef __attribute__((ext_vector_type(8))) short short8;
typedef __attribute__((ext_vector_type(4))) float f32x4;
typedef unsigned long long u64;

__device__ __forceinline__ unsigned short f2b(float f){
  unsigned int u = __builtin_bit_cast(unsigned int, f);
  u += 0x7fffu + ((u >> 16) & 1u);
  return (unsigned short)(u >> 16);
}
__device__ __forceinline__ float b2f(unsigned short v){
  return __builtin_bit_cast(float, ((unsigned int)v) << 16);
}
__device__ __forceinline__ float geluf(float x){
  return 0.5f * x * (1.0f + erff(x * 0.70710678118654752440f));
}
__device__ __forceinline__ float wsum(float v){
  #pragma unroll
  for (int o = 32; o; o >>= 1) v += __shfl_xor(v, o, 64);
  return v;
}
__device__ __forceinline__ u64 pk3t(float a, float b, float c, unsigned tag){
  return (u64)f2b(a) | ((u64)f2b(b) << 16) | ((u64)f2b(c) << 32) | ((u64)(tag & 0xffffu) << 48);
}
__device__ __forceinline__ void st64(u64* p, u64 v){
  __hip_atomic_store(p, v, __ATOMIC_RELAXED, __HIP_MEMORY_SCOPE_AGENT);
}
__device__ __forceinline__ u64 ld64(const u64* p){
  return __hip_atomic_load(p, __ATOMIC_RELAXED, __HIP_MEMORY_SCOPE_AGENT);
}

// ---------------------------------------------------------------------------
// transpose + f32->bf16 : src [768, N] (rows offset by rowoff) -> dst [N, 768]
// ---------------------------------------------------------------------------
__global__ __launch_bounds__(256) void transpose_f2b(
    const float* __restrict__ src, unsigned short* __restrict__ dst,
    int N, int rowoff)
{
  __shared__ unsigned short tile[32][33];
  const int nb = blockIdx.x * 32, kb = blockIdx.y * 32;
  const int tx = threadIdx.x & 31, ty = threadIdx.x >> 5;
  #pragma unroll
  for (int i = 0; i < 4; ++i) {
    int k = kb + ty + 8*i, n = nb + tx;
    unsigned short v = 0;
    if (n < N) v = f2b(src[(size_t)(rowoff + k)*N + n]);
    tile[ty + 8*i][tx] = v;
  }
  __syncthreads();
  #pragma unroll
  for (int i = 0; i < 4; ++i) {
    int n = nb + ty + 8*i;
    if (n < N) dst[(size_t)n*768 + kb + tx] = tile[tx][ty + 8*i];
  }
}

// ---------------------------------------------------------------------------
// f32 transpose: src [R][C] -> dst [C][R]   (R, C multiples of 32)
// ---------------------------------------------------------------------------
__global__ __launch_bounds__(256) void transpose_f32(
    const float* __restrict__ src, float* __restrict__ dst, int R, int C)
{
  __shared__ float tile[32][33];
  const int cb = blockIdx.x * 32, rb = blockIdx.y * 32;
  const int tx = threadIdx.x & 31, ty = threadIdx.x >> 5;
  #pragma unroll
  for (int i = 0; i < 4; ++i)
    tile[ty + 8*i][tx] = src[(size_t)(rb + ty + 8*i)*C + cb + tx];
  __syncthreads();
  #pragma unroll
  for (int i = 0; i < 4; ++i)
    dst[(size_t)(cb + ty + 8*i)*R + rb + tx] = tile[tx][ty + 8*i];
}

// ---------------------------------------------------------------------------
// embedding gather + L2 normalize : emb_all[b*256+t][768]
// ---------------------------------------------------------------------------
__global__ __launch_bounds__(256) void embed_kernel(
    const int* __restrict__ tok, const float* __restrict__ emb,
    float* __restrict__ emb_all)
{
  const int row = blockIdx.x, tid = threadIdx.x;
  const int id = tok[row];
  const float* e = emb + (size_t)id * 768;
  float v0 = e[tid], v1 = e[tid+256], v2 = e[tid+512];
  float ssq = wsum(v0*v0 + v1*v1 + v2*v2);
  __shared__ float red[4];
  if ((tid & 63) == 0) red[tid >> 6] = ssq;
  __syncthreads();
  float inv = 1.0f / fmaxf(sqrtf(red[0]+red[1]+red[2]+red[3]), 1e-12f);
  float* o = emb_all + (size_t)row * 768;
  o[tid] = v0*inv; o[tid+256] = v1*inv; o[tid+512] = v2*inv;
}

// gbias[c] = sum_k c2[k] * Wg[768+k][c]
__global__ void gbias_kernel(const float* __restrict__ c2,
                             const float* __restrict__ Wg,
                             float* __restrict__ gbias)
{
  int c = blockIdx.x * 256 + threadIdx.x;
  if (c >= 768) return;
  float s = 0.f;
  for (int k = 0; k < 768; ++k) s += c2[k] * Wg[(size_t)(768 + k)*768 + c];
  gbias[c] = s;
}

// ---------------------------------------------------------------------------
// GEMM: C[M,N] = A[M,768](f32, bf16-cast) @ B + bias
//   BMODE 0: B = BT bf16 [N,768] (transposed)   BMODE 1: B = f32 [768,N]
// ---------------------------------------------------------------------------
template<int BMODE>
__global__ __launch_bounds__(256) void gemm_kernel(
    const float* __restrict__ A, const void* __restrict__ Bp,
    float* __restrict__ C, const float* __restrict__ bias,
    int M, int N, int q, int r)
{
  const int x = blockIdx.x;
  const int s = blockIdx.y;
  const int mtiles = M >> 6;
  const int cnt_x = q + (x < r ? 1 : 0);
  if (s >= cnt_x * mtiles) return;
  const int off_x = x*q + (x < r ? x : r);
  const int nt = off_x + s / mtiles;
  const int mt = s % mtiles;
  const int m0 = mt << 6, n0 = nt << 6;
  const int w = threadIdx.x >> 6, l = threadIdx.x & 63;
  const int lrow = l & 15, lk8 = (l >> 4) << 3;
  const int arow = m0 + w*16 + lrow;
  f32x4 acc[4] = {f32x4{0,0,0,0}, f32x4{0,0,0,0}, f32x4{0,0,0,0}, f32x4{0,0,0,0}};
  const unsigned short* BT = (const unsigned short*)Bp;
  const float* Bf = (const float*)Bp;

  for (int kk = 0; kk < 768; kk += 32) {
    const float4* ap = (const float4*)(A + (size_t)arow*768 + kk + lk8);
    float4 a0 = ap[0], a1 = ap[1];
    short8 af;
    af[0]=(short)f2b(a0.x); af[1]=(short)f2b(a0.y); af[2]=(short)f2b(a0.z); af[3]=(short)f2b(a0.w);
    af[4]=(short)f2b(a1.x); af[5]=(short)f2b(a1.y); af[6]=(short)f2b(a1.z); af[7]=(short)f2b(a1.w);
    #pragma unroll
    for (int ss = 0; ss < 4; ++ss) {
      const int col = n0 + ss*16 + lrow;
      short8 bf;
      if (BMODE == 0) {
        if (col < N) {
          uint4 raw = *(const uint4*)(BT + (size_t)col*768 + kk + lk8);
          bf = __builtin_bit_cast(short8, raw);
        } else {
          bf = short8{0,0,0,0,0,0,0,0};
        }
      } else {
        #pragma unroll
        for (int j = 0; j < 8; ++j) {
          float v = (col < N) ? Bf[(size_t)(kk + lk8 + j)*N + col] : 0.f;
          bf[j] = (short)f2b(v);
        }
      }
      acc[ss] = __builtin_amdgcn_mfma_f32_16x16x32_bf16(af, bf, acc[ss], 0, 0, 0);
    }
  }
  const int rbase = m0 + w*16 + ((l >> 4) << 2);
  #pragma unroll
  for (int ss = 0; ss < 4; ++ss) {
    const int col = n0 + ss*16 + lrow;
    if (col < N) {
      const float badd = bias ? bias[col] : 0.f;
      #pragma unroll
      for (int rr = 0; rr < 4; ++rr)
        C[(size_t)(rbase + rr)*N + col] = acc[ss][rr] + badd;
    }
  }
}

// ---------------------------------------------------------------------------
// Persistent recurrent kernel: 32 WGs x 256 threads.
// WG g owns cols [g*96,+96) of RV0T and [g*24,+24) of V1T/W1T/W2T/W2GT/RWtT,
// processed as 8 virtual sub-WGs (vg): gv = g*8+vg owns 12 RV0 / 3 narrow cols.
// Weights read from GLOBAL (transposed [col][K], coalesced over k).
// Transport words identical to R3: a1_if [par][4 bb][1024 w] (w = 3 cols),
// tg/u/pre_if [par][1024 w] (w = G*4+bb, G = gv = cols G*3..+2).
// Tag for step t = t+1; h-phase of step t polls tag t.
// ---------------------------------------------------------------------------
__global__ __launch_bounds__(256) void recur_kernel(
    const float* __restrict__ RV0T, const float* __restrict__ RWtT,
    const float* __restrict__ W1T,  const float* __restrict__ W2T,
    const float* __restrict__ W2GT, const float* __restrict__ V1T,
    const float* __restrict__ embV0, const float* __restrict__ embWg,
    const float* __restrict__ gbias, const float* __restrict__ emb_all,
    const float* __restrict__ b1, const float* __restrict__ c1,
    const float* __restrict__ c2, const float* __restrict__ gam,
    const float* __restrict__ bet, float* __restrict__ h_all,
    u64* __restrict__ a1_if, u64* __restrict__ tg_if,
    u64* __restrict__ u_if,  u64* __restrict__ pre_if)
{
  __shared__ float sX[4*768];            // 12288 B (h / cb / u)
  __shared__ float sX2[4*768];           // 12288 B (x2 state, replicated)
  __shared__ unsigned short sA1[4*3072]; // 24576 B (a1 staged)
  __shared__ float sRed[256];            // 1024 B
  __shared__ float sTf[96];              // 384 B  (tf slices, all 8 vg)

  const int g = blockIdx.x, tid = threadIdx.x;
  const int wv = tid >> 6, lane = tid & 63;

  for (int i = tid; i < 4*768; i += 256) sX2[i] = 0.f;
  __syncthreads();

  for (int t = 0; t <= 256; ++t) {
    // ================= h_{t-1} from fused pre-LN words =================
    if (t == 0) {
      for (int i = tid; i < 4*768; i += 256) sX[i] = 0.f;
    } else {
      const int parh = (t - 1) & 1;
      const unsigned tagh = (unsigned)t;
      const int wb = parh*1024 + lane*16 + wv;
      u64 w4[4]; bool ok;
      do {
        #pragma unroll
        for (int qq = 0; qq < 4; ++qq) w4[qq] = ld64(pre_if + wb + qq*4);
        ok = true;
        #pragma unroll
        for (int qq = 0; qq < 4; ++qq) ok &= ((unsigned)(w4[qq] >> 48) == tagh);
      } while (__builtin_expect(!ok, 0));
      float pre[12];
      #pragma unroll
      for (int qq = 0; qq < 4; ++qq) {
        pre[qq*3+0] = b2f((unsigned short)(w4[qq]));
        pre[qq*3+1] = b2f((unsigned short)(w4[qq] >> 16));
        pre[qq*3+2] = b2f((unsigned short)(w4[qq] >> 32));
      }
      float s1 = 0.f;
      #pragma unroll
      for (int i = 0; i < 12; ++i) s1 += pre[i];
      s1 = wsum(s1);
      const float mean = s1 * (1.0f/768.0f);
      float s2 = 0.f;
      #pragma unroll
      for (int i = 0; i < 12; ++i) { const float d = pre[i] - mean; s2 += d*d; }
      s2 = wsum(s2);
      const float rstd = 1.0f / sqrtf(s2*(1.0f/768.0f) + 1e-5f);
      const int k0 = lane*12;
      float hv[12];
      #pragma unroll
      for (int i = 0; i < 12; ++i) {
        hv[i] = (pre[i] - mean)*rstd*gam[k0+i] + bet[k0+i];
        sX[wv*768 + k0 + i] = hv[i];
      }
      if (g == 0) {
        float* hp = h_all + (size_t)(wv*256 + t - 1)*768 + k0;
        #pragma unroll
        for (int i = 0; i < 12; ++i) hp[i] = hv[i];
      }
    }
    __syncthreads();
    if (t == 256) break;
    const int par = t & 1;
    const unsigned tagp = (unsigned)(t + 1);

    // ================= P1: a1 (96 cols), tf (24 cols) =================
    {
      const int cg = tid >> 6, ks = tid & 63;
      for (int vg = 0; vg < 8; ++vg) {
        const int gv = g*8 + vg;
        float acc[4][4] = {};
        for (int i = 0; i < 12; ++i) {
          const int k = ks + 64*i;
          const float x0 = sX[k], x1 = sX[768+k], x2v = sX[1536+k], x3 = sX[2304+k];
          #pragma unroll
          for (int j = 0; j < 4; ++j) {
            float w = 0.f;
            if (cg < 3)      w = RV0T[(size_t)(gv*12 + cg*4 + j)*768 + k];
            else if (j < 3)  w = RWtT[(size_t)(gv*3 + j)*768 + k];
            acc[j][0] += w*x0; acc[j][1] += w*x1; acc[j][2] += w*x2v; acc[j][3] += w*x3;
          }
        }
        #pragma unroll
        for (int j = 0; j < 4; ++j)
          #pragma unroll
          for (int bb = 0; bb < 4; ++bb) {
            const float v = wsum(acc[j][bb]);
            if (lane == 0) sRed[cg*16 + j*4 + bb] = v;
          }
        __syncthreads();
        if (tid < 16) {               // a1 words: bb = tid&3, w = tid>>2
          const int bb = tid & 3, w = tid >> 2;
          float v[3];
          #pragma unroll
          for (int s = 0; s < 3; ++s) {
            const int c = w*3 + s;    // 0..11 within vg
            const float raw = sRed[(c >> 2)*16 + (c & 3)*4 + bb];
            v[s] = geluf(embV0[(size_t)(bb*256 + t)*3072 + gv*12 + c] + 0.4f*raw);
          }
          st64(a1_if + par*4096 + bb*1024 + gv*4 + w, pk3t(v[0], v[1], v[2], tagp));
        } else if (tid < 20) {        // stash tf slice for P4
          const int bb = tid - 16;
          sTf[vg*12 + 0*4 + bb] = sRed[48 + bb];
          sTf[vg*12 + 1*4 + bb] = sRed[52 + bb];
          sTf[vg*12 + 2*4 + bb] = sRed[56 + bb];
        }
        __syncthreads();
      }
    }

    // ================= P2: target (24 cols) =================
    {
      // poll + stage full a1 (16 tagged words per thread)
      const u64* basep = a1_if + par*4096;
      u64 x[16]; bool ok;
      do {
        #pragma unroll
        for (int i = 0; i < 16; ++i) x[i] = ld64(basep + i*256 + tid);
        ok = true;
        #pragma unroll
        for (int i = 0; i < 16; ++i) ok &= ((unsigned)(x[i] >> 48) == tagp);
      } while (__builtin_expect(!ok, 0));
      #pragma unroll
      for (int i = 0; i < 16; ++i) {
        const int widx = i*256 + tid;       // [0,4096)
        const int bb = widx >> 10, j = widx & 1023;
        sA1[bb*3072 + 3*j + 0] = (unsigned short)(x[i]);
        sA1[bb*3072 + 3*j + 1] = (unsigned short)(x[i] >> 16);
        sA1[bb*3072 + 3*j + 2] = (unsigned short)(x[i] >> 32);
      }
      __syncthreads();
      for (int vg = 0; vg < 8; ++vg) {
        const int gv = g*8 + vg;
        float acc[3][4] = {};
        for (int ip = 0; ip < 12; ++ip) {
          const int k = lane + 64*(wv + 4*ip);
          float xv[4];
          #pragma unroll
          for (int bb = 0; bb < 4; ++bb) xv[bb] = b2f(sA1[bb*3072 + k]);
          #pragma unroll
          for (int c = 0; c < 3; ++c) {
            const float w = V1T[(size_t)(gv*3 + c)*3072 + k];
            acc[c][0] += w*xv[0]; acc[c][1] += w*xv[1]; acc[c][2] += w*xv[2]; acc[c][3] += w*xv[3];
          }
        }
        #pragma unroll
        for (int c = 0; c < 3; ++c)
          #pragma unroll
          for (int bb = 0; bb < 4; ++bb) {
            const float v = wsum(acc[c][bb]);
            if (lane == 0) sRed[wv*12 + c*4 + bb] = v;
          }
        __syncthreads();
        if (tid < 4) {
          const int bb = tid;
          float v[3];
          #pragma unroll
          for (int c = 0; c < 3; ++c) {
            float s = sRed[c*4+bb] + sRed[12 + c*4+bb] + sRed[24 + c*4+bb] + sRed[36 + c*4+bb];
            v[c] = geluf(s + b1[gv*3 + c]);
          }
          st64(tg_if + par*1024 + gv*4 + bb, pk3t(v[0], v[1], v[2], tagp));
        }
        __syncthreads();
      }
    }

    // ================= P3: x2 EMA, cb, u (24 cols) =================
    {
      const int wb = par*1024 + lane*16 + wv;
      u64 wt4[4]; bool ok;
      do {
        #pragma unroll
        for (int qq = 0; qq < 4; ++qq) wt4[qq] = ld64(tg_if + wb + qq*4);
        ok = true;
        #pragma unroll
        for (int qq = 0; qq < 4; ++qq) ok &= ((unsigned)(wt4[qq] >> 48) == tagp);
      } while (__builtin_expect(!ok, 0));
      float tv[12];
      #pragma unroll
      for (int qq = 0; qq < 4; ++qq) {
        tv[qq*3+0] = b2f((unsigned short)(wt4[qq]));
        tv[qq*3+1] = b2f((unsigned short)(wt4[qq] >> 16));
        tv[qq*3+2] = b2f((unsigned short)(wt4[qq] >> 32));
      }
      const int xb = wv*768 + lane*12;
      float xv2[12];
      float ssqT = 0.f, ssqX = 0.f;
      #pragma unroll
      for (int i = 0; i < 12; ++i) {
        float xx = sX2[xb + i];
        const float tt = tv[i];
        #pragma unroll
        for (int rr = 0; rr < 10; ++rr) xx = 0.5f*xx + 0.5f*tt;
        sX2[xb + i] = xx; xv2[i] = xx;
        ssqT += tt*tt; ssqX += xx*xx;
      }
      ssqT = wsum(ssqT); ssqX = wsum(ssqX);
      const float invT = 1.0f / fmaxf(sqrtf(ssqT), 1e-12f);
      const float invX = 1.0f / fmaxf(sqrtf(ssqX), 1e-12f);
      #pragma unroll
      for (int i = 0; i < 12; ++i) sX[xb + i] = 0.5f*(tv[i]*invT + xv2[i]*invX);
      __syncthreads();
      for (int vg = 0; vg < 8; ++vg) {
        const int gv = g*8 + vg;
        float acc[3][4] = {};
        #pragma unroll
        for (int ip = 0; ip < 3; ++ip) {
          const int k = lane + 64*(wv + 4*ip);
          float xv[4];
          #pragma unroll
          for (int bb = 0; bb < 4; ++bb) xv[bb] = sX[bb*768 + k];
          #pragma unroll
          for (int c = 0; c < 3; ++c) {
            const float w = W1T[(size_t)(gv*3 + c)*768 + k];
            acc[c][0] += w*xv[0]; acc[c][1] += w*xv[1]; acc[c][2] += w*xv[2]; acc[c][3] += w*xv[3];
          }
        }
        #pragma unroll
        for (int c = 0; c < 3; ++c)
          #pragma unroll
          for (int bb = 0; bb < 4; ++bb) {
            const float v = wsum(acc[c][bb]);
            if (lane == 0) sRed[wv*12 + c*4 + bb] = v;
          }
        __syncthreads();
        if (tid < 4) {
          const int bb = tid;
          float v[3];
          #pragma unroll
          for (int c = 0; c < 3; ++c) {
            float s = sRed[c*4+bb] + sRed[12 + c*4+bb] + sRed[24 + c*4+bb] + sRed[36 + c*4+bb];
            v[c] = geluf(s + c1[gv*3 + c]);
          }
          st64(u_if + par*1024 + gv*4 + bb, pk3t(v[0], v[1], v[2], tagp));
        }
        __syncthreads();
      }
    }

    // ================= P4: cf/gv -> fused pre-LN (24 cols) =================
    {
      const int wb = par*1024 + lane*16 + wv;
      u64 wu4[4]; bool ok;
      do {
        #pragma unroll
        for (int qq = 0; qq < 4; ++qq) wu4[qq] = ld64(u_if + wb + qq*4);
        ok = true;
        #pragma unroll
        for (int qq = 0; qq < 4; ++qq) ok &= ((unsigned)(wu4[qq] >> 48) == tagp);
      } while (__builtin_expect(!ok, 0));
      const int xb = wv*768 + lane*12;
      #pragma unroll
      for (int qq = 0; qq < 4; ++qq) {
        sX[xb + qq*3 + 0] = b2f((unsigned short)(wu4[qq]));
        sX[xb + qq*3 + 1] = b2f((unsigned short)(wu4[qq] >> 16));
        sX[xb + qq*3 + 2] = b2f((unsigned short)(wu4[qq] >> 32));
      }
      __syncthreads();
      for (int vg = 0; vg < 8; ++vg) {
        const int gv = g*8 + vg;
        float acc[6][4] = {};
        #pragma unroll
        for (int ip = 0; ip < 3; ++ip) {
          const int k = lane + 64*(wv + 4*ip);
          float xv[4];
          #pragma unroll
          for (int bb = 0; bb < 4; ++bb) xv[bb] = sX[bb*768 + k];
          #pragma unroll
          for (int c = 0; c < 6; ++c) {
            const float w = (c < 3) ? W2T[(size_t)(gv*3 + c)*768 + k]
                                    : W2GT[(size_t)(gv*3 + (c-3))*768 + k];
            acc[c][0] += w*xv[0]; acc[c][1] += w*xv[1]; acc[c][2] += w*xv[2]; acc[c][3] += w*xv[3];
          }
        }
        #pragma unroll
        for (int c = 0; c < 6; ++c)
          #pragma unroll
          for (int bb = 0; bb < 4; ++bb) {
            const float v = wsum(acc[c][bb]);
            if (lane == 0) sRed[wv*24 + c*4 + bb] = v;
          }
        __syncthreads();
        if (tid < 4) {
          const int bb = tid;
          float pre3[3];
          #pragma unroll
          for (int c = 0; c < 3; ++c) {
            const int col = gv*3 + c;
            float sc = sRed[c*4+bb] + sRed[24 + c*4+bb] + sRed[48 + c*4+bb] + sRed[72 + c*4+bb];
            const float cf = sc + c2[col];
            const int cc = c + 3;
            float sg = sRed[cc*4+bb] + sRed[24 + cc*4+bb] + sRed[48 + cc*4+bb] + sRed[72 + cc*4+bb];
            const float gv_ = sg + embWg[(size_t)(bb*256 + t)*768 + col] + gbias[col];
            const float gg = 1.0f / (1.0f + expf(-gv_));
            const float em = emb_all[(size_t)(bb*256 + t)*768 + col];
            pre3[c] = gg*(cf + 0.4f*sTf[vg*12 + c*4 + bb]) + (1.0f - gg)*em;
          }
          st64(pre_if + par*1024 + gv*4 + bb, pk3t(pre3[0], pre3[1], pre3[2], tagp));
        }
        __syncthreads();
      }
    }
  }
}

// ---------------------------------------------------------------------------
// host
// ---------------------------------------------------------------------------
static void launch_gemm(const float* A, const void* B, float* C, const float* bias,
                        int M, int N, int bmode, hipStream_t st)
{
  const int ntiles = (N + 63) / 64;
  const int q = ntiles / 8, r = ntiles % 8;
  const int mtiles = M / 64;
  const int smax = (q + (r ? 1 : 0)) * mtiles;
  dim3 grid(8, smax);
  if (bmode == 0) gemm_kernel<0><<<grid, 256, 0, st>>>(A, B, C, bias, M, N, q, r);
  else            gemm_kernel<1><<<grid, 256, 0, st>>>(A, B, C, bias, M, N, q, r);
}

extern "C" void kernel_launch(void* const* d_in, const int* in_sizes, int n_in,
                              void* d_out, int out_size, void* d_ws, size_t ws_size,
                              hipStream_t stream)
{
  const int*   tok   = (const int*)d_in[0];
  const float* emb   = (const float*)d_in[1];
  const float* V0    = (const float*)d_in[2];
  const float* b0    = (const float*)d_in[3];
  const float* V1    = (const float*)d_in[4];
  const float* b1    = (const float*)d_in[5];
  const float* W1    = (const float*)d_in[6];
  const float* c1    = (const float*)d_in[7];
  const float* W2    = (const float*)d_in[8];
  const float* c2    = (const float*)d_in[9];
  const float* Wg    = (const float*)d_in[10];
  const float* bg    = (const float*)d_in[11];
  const float* Wt    = (const float*)d_in[12];
  const float* gamma = (const float*)d_in[13];
  const float* beta  = (const float*)d_in[14];
  const float* Wl    = (const float*)d_in[15];
  const float* Rw    = (const float*)d_in[16];

  float* outf = (float*)d_out;
  // scratch carved from d_out (all consumed before the final GEMM overwrites)
  float* emb_all = outf + 0;                    //  786432
  float* RV0     = outf + 786432;               // 2359296
  float* RWt     = outf + 3145728;              //  589824
  float* W2G     = outf + 3735552;              //  589824
  float* embV0   = outf + 4325376;              // 3145728
  float* embWg   = outf + 7471104;              //  786432
  float* gbias   = outf + 8257536;              //    1024
  unsigned short* V0T  = (unsigned short*)(outf + 8258560);   // 2359296 el
  unsigned short* WtT  = (unsigned short*)(outf + 9438208);   //  589824 el
  unsigned short* WgTT = (unsigned short*)(outf + 9733120);   //  589824 el
  unsigned short* WgBT = (unsigned short*)(outf + 10028032);  //  589824 el
  float* RV0T = outf + 10322944;                // 2359296
  float* V1T  = outf + 12682240;                // 2359296
  float* W1T  = outf + 15041536;                //  589824
  float* W2T  = outf + 15631360;                //  589824
  float* W2GT = outf + 16221184;                //  589824
  float* RWtT = outf + 16811008;                //  589824
  u64* a1_if  = (u64*)(outf + 17400832);        // 8192 u64
  u64* tg_if  = (u64*)(outf + 17417216);        // 2048 u64
  u64* u_if   = (u64*)(outf + 17421312);        // 2048 u64
  u64* pre_if = (u64*)(outf + 17425408);        // 2048 u64
                                                // end: 17429504 < 51.46M

  float* h_all = (float*)d_ws;                                // 786432 f32
  unsigned short* WlT = (unsigned short*)((char*)d_ws + 786432*4);
  const bool bigws = ws_size >= (size_t)(786432*4) + (size_t)38597376*2 + 256;

  // transposed bf16 copies of GEMM B operands
  transpose_f2b<<<dim3(96, 24),   256, 0, stream>>>(V0, V0T, 3072, 0);
  transpose_f2b<<<dim3(24, 24),   256, 0, stream>>>(Wt, WtT, 768, 0);
  transpose_f2b<<<dim3(24, 24),   256, 0, stream>>>(Wg, WgTT, 768, 0);
  transpose_f2b<<<dim3(24, 24),   256, 0, stream>>>(Wg, WgBT, 768, 768);
  if (bigws)
    transpose_f2b<<<dim3(1572, 24), 256, 0, stream>>>(Wl, WlT, 50257, 0);

  embed_kernel<<<1024, 256, 0, stream>>>(tok, emb, emb_all);
  gbias_kernel<<<3, 256, 0, stream>>>(c2, Wg, gbias);

  // f32 transposes of raw weights for the recurrence (dst [col][K])
  transpose_f32<<<dim3(24, 96), 256, 0, stream>>>(V1, V1T, 3072, 768);
  transpose_f32<<<dim3(24, 24), 256, 0, stream>>>(W1, W1T, 768, 768);
  transpose_f32<<<dim3(24, 24), 256, 0, stream>>>(W2, W2T, 768, 768);

  // fused-weight + per-token precompute GEMMs (bf16 MFMA, fp32 out)
  launch_gemm(Rw,      V0T,  RV0,   nullptr, 768,  3072, 0, stream);
  launch_gemm(Rw,      WtT,  RWt,   nullptr, 768,  768,  0, stream);
  launch_gemm(W2,      WgBT, W2G,   nullptr, 768,  768,  0, stream);
  launch_gemm(emb_all, V0T,  embV0, b0,      1024, 3072, 0, stream);
  launch_gemm(emb_all, WgTT, embWg, bg,      1024, 768,  0, stream);

  // transposes of fused weights (after their GEMMs)
  transpose_f32<<<dim3(96, 24), 256, 0, stream>>>(RV0, RV0T, 768, 3072);
  transpose_f32<<<dim3(24, 24), 256, 0, stream>>>(RWt, RWtT, 768, 768);
  transpose_f32<<<dim3(24, 24), 256, 0, stream>>>(W2G, W2GT, 768, 768);

  // the sequential part: 32 WGs
  recur_kernel<<<32, 256, 0, stream>>>(
      RV0T, RWtT, W1T, W2T, W2GT, V1T, embV0, embWg, gbias, emb_all,
      b1, c1, c2, gamma, beta, h_all,
      a1_if, tg_if, u_if, pre_if);

  // deferred lm_head: logits[b*256+t][v] = h_all @ Wl
  if (bigws) launch_gemm(h_all, WlT, outf, nullptr, 1024, 50257, 0, stream);
  else       launch_gemm(h_all, Wl,  outf, nullptr, 1024, 50257, 1, stream);
}

// Round 6
// 10985.020 us; speedup vs baseline: 3.4951x; 3.4951x over previous
//
#include <hip/hip_runtime.h>

// ============================================================================
// AgnisV5: sequential recurrence (4-phase persistent kernel, weights in LDS)
//          + deferred batched lm_head GEMM (bf16 MFMA).
//
// Round-6 change: FLAG-GATED PLAIN-LOAD TRANSPORT (implicit per-XCD L2 fanout).
// R3's floor was sc1 read BW: 256 consumers x full payload ~14MB/step at
// ~400GB/s ~= the 39us/step. Now transport buffers are WRITE-ONCE (indexed by
// step t, no reuse within a dispatch), so consumers may read them with PLAIN
// loads: first WG per XCD misses L2 -> pulls fresh line from IF$; remaining 31
// WGs hit local L2. Release protocol (all primitives proven in R2/R3):
//   producer: st64(sc1) payload -> s_waitcnt vmcnt(0) -> __syncthreads
//             -> tid==0 st32(sc1) per-WG flag = t+1   (flags memset 0/launch)
//   consumer: thread tid sc1-polls flag[tid] >= want -> __syncthreads
//             -> plain vector loads of payload.
// Within-dispatch staleness impossible (write-once); across dispatches the
// L1/L2 are invalidated at dispatch boundaries (relied on since R1 for the
// GEMM->recur weight flow); replay values are bit-identical regardless.
// P4 emits the fused pre-LN slice sigma(gv)*(cf+0.4tf)+(1-sigma)*emb (tf kept
// in LDS), so the h-phase gathers 4 words/thread.
// ============================================================================

typedef __attribute__((ext_vector_type(8))) short short8;
typedef __attribute__((ext_vector_type(4))) float f32x4;
typedef unsigned long long u64;

__device__ __forceinline__ unsigned short f2b(float f){
  unsigned int u = __builtin_bit_cast(unsigned int, f);
  u += 0x7fffu + ((u >> 16) & 1u);
  return (unsigned short)(u >> 16);
}
__device__ __forceinline__ float b2f(unsigned short v){
  return __builtin_bit_cast(float, ((unsigned int)v) << 16);
}
__device__ __forceinline__ float geluf(float x){
  return 0.5f * x * (1.0f + erff(x * 0.70710678118654752440f));
}
__device__ __forceinline__ float wsum(float v){
  #pragma unroll
  for (int o = 32; o; o >>= 1) v += __shfl_xor(v, o, 64);
  return v;
}
__device__ __forceinline__ u64 pk3t(float a, float b, float c, unsigned tag){
  return (u64)f2b(a) | ((u64)f2b(b) << 16) | ((u64)f2b(c) << 32) | ((u64)(tag & 0xffffu) << 48);
}
// sc1 (IF$-coherent) accessors — the only cross-XCD-visible ops we use
__device__ __forceinline__ void st64(u64* p, u64 v){
  __hip_atomic_store(p, v, __ATOMIC_RELAXED, __HIP_MEMORY_SCOPE_AGENT);
}
__device__ __forceinline__ void stflag(int* p, int v){
  __hip_atomic_store(p, v, __ATOMIC_RELAXED, __HIP_MEMORY_SCOPE_AGENT);
}
__device__ __forceinline__ int ldflag(const int* p){
  return __hip_atomic_load(p, __ATOMIC_RELAXED, __HIP_MEMORY_SCOPE_AGENT);
}
__device__ __forceinline__ void vm0(){ asm volatile("s_waitcnt vmcnt(0)" ::: "memory"); }

// flag array indices
#define FA1  0
#define FTG  256
#define FU   512
#define FPRE 768

// ---------------------------------------------------------------------------
// transpose + f32->bf16 : src [768, N] (rows offset by rowoff) -> dst [N, 768]
// ---------------------------------------------------------------------------
__global__ __launch_bounds__(256) void transpose_f2b(
    const float* __restrict__ src, unsigned short* __restrict__ dst,
    int N, int rowoff)
{
  __shared__ unsigned short tile[32][33];
  const int nb = blockIdx.x * 32, kb = blockIdx.y * 32;
  const int tx = threadIdx.x & 31, ty = threadIdx.x >> 5;
  #pragma unroll
  for (int i = 0; i < 4; ++i) {
    int k = kb + ty + 8*i, n = nb + tx;
    unsigned short v = 0;
    if (n < N) v = f2b(src[(size_t)(rowoff + k)*N + n]);
    tile[ty + 8*i][tx] = v;
  }
  __syncthreads();
  #pragma unroll
  for (int i = 0; i < 4; ++i) {
    int n = nb + ty + 8*i;
    if (n < N) dst[(size_t)n*768 + kb + tx] = tile[tx][ty + 8*i];
  }
}

// ---------------------------------------------------------------------------
// embedding gather + L2 normalize : emb_all[b*256+t][768]
// ---------------------------------------------------------------------------
__global__ __launch_bounds__(256) void embed_kernel(
    const int* __restrict__ tok, const float* __restrict__ emb,
    float* __restrict__ emb_all)
{
  const int row = blockIdx.x, tid = threadIdx.x;
  const int id = tok[row];
  const float* e = emb + (size_t)id * 768;
  float v0 = e[tid], v1 = e[tid+256], v2 = e[tid+512];
  float ssq = wsum(v0*v0 + v1*v1 + v2*v2);
  __shared__ float red[4];
  if ((tid & 63) == 0) red[tid >> 6] = ssq;
  __syncthreads();
  float inv = 1.0f / fmaxf(sqrtf(red[0]+red[1]+red[2]+red[3]), 1e-12f);
  float* o = emb_all + (size_t)row * 768;
  o[tid] = v0*inv; o[tid+256] = v1*inv; o[tid+512] = v2*inv;
}

// gbias[c] = sum_k c2[k] * Wg[768+k][c]
__global__ void gbias_kernel(const float* __restrict__ c2,
                             const float* __restrict__ Wg,
                             float* __restrict__ gbias)
{
  int c = blockIdx.x * 256 + threadIdx.x;
  if (c >= 768) return;
  float s = 0.f;
  for (int k = 0; k < 768; ++k) s += c2[k] * Wg[(size_t)(768 + k)*768 + c];
  gbias[c] = s;
}

// ---------------------------------------------------------------------------
// GEMM: C[M,N] = A[M,768](f32, bf16-cast) @ B + bias
//   BMODE 0: B = BT bf16 [N,768] (transposed)   BMODE 1: B = f32 [768,N]
// ---------------------------------------------------------------------------
template<int BMODE>
__global__ __launch_bounds__(256) void gemm_kernel(
    const float* __restrict__ A, const void* __restrict__ Bp,
    float* __restrict__ C, const float* __restrict__ bias,
    int M, int N, int q, int r)
{
  const int x = blockIdx.x;
  const int s = blockIdx.y;
  const int mtiles = M >> 6;
  const int cnt_x = q + (x < r ? 1 : 0);
  if (s >= cnt_x * mtiles) return;
  const int off_x = x*q + (x < r ? x : r);
  const int nt = off_x + s / mtiles;
  const int mt = s % mtiles;
  const int m0 = mt << 6, n0 = nt << 6;
  const int w = threadIdx.x >> 6, l = threadIdx.x & 63;
  const int lrow = l & 15, lk8 = (l >> 4) << 3;
  const int arow = m0 + w*16 + lrow;
  f32x4 acc[4] = {f32x4{0,0,0,0}, f32x4{0,0,0,0}, f32x4{0,0,0,0}, f32x4{0,0,0,0}};
  const unsigned short* BT = (const unsigned short*)Bp;
  const float* Bf = (const float*)Bp;

  for (int kk = 0; kk < 768; kk += 32) {
    const float4* ap = (const float4*)(A + (size_t)arow*768 + kk + lk8);
    float4 a0 = ap[0], a1 = ap[1];
    short8 af;
    af[0]=(short)f2b(a0.x); af[1]=(short)f2b(a0.y); af[2]=(short)f2b(a0.z); af[3]=(short)f2b(a0.w);
    af[4]=(short)f2b(a1.x); af[5]=(short)f2b(a1.y); af[6]=(short)f2b(a1.z); af[7]=(short)f2b(a1.w);
    #pragma unroll
    for (int ss = 0; ss < 4; ++ss) {
      const int col = n0 + ss*16 + lrow;
      short8 bf;
      if (BMODE == 0) {
        if (col < N) {
          uint4 raw = *(const uint4*)(BT + (size_t)col*768 + kk + lk8);
          bf = __builtin_bit_cast(short8, raw);
        } else {
          bf = short8{0,0,0,0,0,0,0,0};
        }
      } else {
        #pragma unroll
        for (int j = 0; j < 8; ++j) {
          float v = (col < N) ? Bf[(size_t)(kk + lk8 + j)*N + col] : 0.f;
          bf[j] = (short)f2b(v);
        }
      }
      acc[ss] = __builtin_amdgcn_mfma_f32_16x16x32_bf16(af, bf, acc[ss], 0, 0, 0);
    }
  }
  const int rbase = m0 + w*16 + ((l >> 4) << 2);
  #pragma unroll
  for (int ss = 0; ss < 4; ++ss) {
    const int col = n0 + ss*16 + lrow;
    if (col < N) {
      const float badd = bias ? bias[col] : 0.f;
      #pragma unroll
      for (int rr = 0; rr < 4; ++rr)
        C[(size_t)(rbase + rr)*N + col] = acc[ss][rr] + badd;
    }
  }
}

// ---------------------------------------------------------------------------
// Persistent recurrent kernel: 256 WGs (1/CU), 256 threads.
// WG g owns cols [g*12,+12) of RV0 and [g*3,+3) of V1/W1/W2/W2G/RWt in LDS.
// Transport: write-once step-indexed buffers + per-WG flags (see header).
//   a1_if : [257 t][4 bb][1024 w] u64, word j = cols 3j..3j+2
//   tg/u/pre_if : [257 t][1024 w] u64, word = G*4+bb -> cols G*3..G*3+2
// ---------------------------------------------------------------------------
__global__ __launch_bounds__(256) void recur_kernel(
    const float* __restrict__ RV0, const float* __restrict__ RWt,
    const float* __restrict__ W1,  const float* __restrict__ W2,
    const float* __restrict__ W2G, const float* __restrict__ V1,
    const float* __restrict__ embV0, const float* __restrict__ embWg,
    const float* __restrict__ gbias, const float* __restrict__ emb_all,
    const float* __restrict__ b1, const float* __restrict__ c1,
    const float* __restrict__ c2, const float* __restrict__ gam,
    const float* __restrict__ bet, float* __restrict__ h_all,
    u64* __restrict__ a1_if, u64* __restrict__ tg_if,
    u64* __restrict__ u_if,  u64* __restrict__ pre_if,
    int* __restrict__ flg)
{
  __shared__ float sRV0[12*768];        // 36864 B
  __shared__ float sV1[3*3072];         // 36864 B
  __shared__ float sW1[3*768];
  __shared__ float sW2[3*768];
  __shared__ float sW2G[3*768];
  __shared__ float sRWt[3*768];         // 4 x 9216 B
  __shared__ float sX[4*768];           // 12288 B
  __shared__ float sX2[4*768];          // 12288 B
  __shared__ unsigned short sA1[4*3072];// 24576 B
  __shared__ float sRed[240];           // 960 B
  __shared__ float sTf[16];             // 64 B   -- total 160768 B

  const int g = blockIdx.x, tid = threadIdx.x;
  const int wv = tid >> 6, lane = tid & 63;

  // ---- load weight slices into LDS ----
  for (int i = tid; i < 12*768; i += 256) {
    int k = i / 12, c = i - k*12;
    sRV0[c*768 + k] = RV0[(size_t)k*3072 + g*12 + c];
  }
  for (int i = tid; i < 3*3072; i += 256) {
    int k = i / 3, c = i - k*3;
    sV1[c*3072 + k] = V1[(size_t)k*768 + g*3 + c];
  }
  for (int i = tid; i < 3*768; i += 256) {
    int k = i / 3, c = i - k*3;
    const int gc = g*3 + c;
    sW1[c*768 + k]  = W1[(size_t)k*768 + gc];
    sW2[c*768 + k]  = W2[(size_t)k*768 + gc];
    sW2G[c*768 + k] = W2G[(size_t)k*768 + gc];
    sRWt[c*768 + k] = RWt[(size_t)k*768 + gc];
  }
  for (int i = tid; i < 4*768; i += 256) sX2[i] = 0.f;
  __syncthreads();

  for (int t = 0; t <= 256; ++t) {
    // ================= h_{t-1} from fused pre-LN words =================
    if (t == 0) {
      for (int i = tid; i < 4*768; i += 256) sX[i] = 0.f;
    } else {
      while (ldflag(flg + FPRE + tid) < t) __builtin_amdgcn_s_sleep(1);
      __syncthreads();
      const u64* pm = pre_if + (size_t)(t-1)*1024 + lane*16 + wv;
      u64 w4[4];
      #pragma unroll
      for (int qq = 0; qq < 4; ++qq) w4[qq] = pm[qq*4];   // plain, L2-served
      float pre[12];
      #pragma unroll
      for (int qq = 0; qq < 4; ++qq) {
        pre[qq*3+0] = b2f((unsigned short)(w4[qq]));
        pre[qq*3+1] = b2f((unsigned short)(w4[qq] >> 16));
        pre[qq*3+2] = b2f((unsigned short)(w4[qq] >> 32));
      }
      float s1 = 0.f;
      #pragma unroll
      for (int i = 0; i < 12; ++i) s1 += pre[i];
      s1 = wsum(s1);
      const float mean = s1 * (1.0f/768.0f);
      float s2 = 0.f;
      #pragma unroll
      for (int i = 0; i < 12; ++i) { const float d = pre[i] - mean; s2 += d*d; }
      s2 = wsum(s2);
      const float rstd = 1.0f / sqrtf(s2*(1.0f/768.0f) + 1e-5f);
      const int k0 = lane*12;
      float hv[12];
      #pragma unroll
      for (int i = 0; i < 12; ++i) {
        hv[i] = (pre[i] - mean)*rstd*gam[k0+i] + bet[k0+i];
        sX[wv*768 + k0 + i] = hv[i];
      }
      if (g == 0) {
        float* hp = h_all + (size_t)(wv*256 + t - 1)*768 + k0;
        #pragma unroll
        for (int i = 0; i < 12; ++i) hp[i] = hv[i];
      }
    }
    __syncthreads();
    if (t == 256) break;
    const unsigned tagp = (unsigned)(t + 1);

    // ================= P1: a1 slice (12 cols), tf slice (LDS stash) ========
    {
      const int cg = tid >> 6, ks = tid & 63;
      float acc[4][4] = {};
      for (int i = 0; i < 12; ++i) {
        const int k = ks + 64*i;
        const float x0 = sX[k], x1 = sX[768+k], x2v = sX[1536+k], x3 = sX[2304+k];
        #pragma unroll
        for (int j = 0; j < 4; ++j) {
          float w;
          if (cg < 3) w = sRV0[(cg*4 + j)*768 + k];
          else        w = (j < 3) ? sRWt[j*768 + k] : 0.f;
          acc[j][0] += w*x0; acc[j][1] += w*x1; acc[j][2] += w*x2v; acc[j][3] += w*x3;
        }
      }
      #pragma unroll
      for (int j = 0; j < 4; ++j)
        #pragma unroll
        for (int bb = 0; bb < 4; ++bb) {
          const float v = wsum(acc[j][bb]);
          if (lane == 0) sRed[cg*16 + j*4 + bb] = v;
        }
      __syncthreads();
      if (tid < 16) {               // 16 a1 words: bb = tid&3, w = tid>>2
        const int bb = tid & 3, w = tid >> 2;
        float v[3];
        #pragma unroll
        for (int s = 0; s < 3; ++s) {
          const int c = w*3 + s;    // 0..11
          const float raw = sRed[(c >> 2)*16 + (c & 3)*4 + bb];
          v[s] = geluf(embV0[(size_t)(bb*256 + t)*3072 + g*12 + c] + 0.4f*raw);
        }
        st64(a1_if + (size_t)t*4096 + bb*1024 + g*4 + w, pk3t(v[0], v[1], v[2], tagp));
      } else if (tid < 20) {        // stash tf slice for P4's fused pre
        const int bb = tid - 16;
        sTf[bb]     = sRed[48 + bb];
        sTf[4 + bb] = sRed[52 + bb];
        sTf[8 + bb] = sRed[56 + bb];
      }
      vm0();
      __syncthreads();
      if (tid == 0) stflag(flg + FA1 + g, t + 1);
    }

    // ================= P2: target slice =================
    {
      while (ldflag(flg + FA1 + tid) < t + 1) __builtin_amdgcn_s_sleep(1);
      __syncthreads();
      const u64* basep = a1_if + (size_t)t*4096;
      u64 x[16];
      #pragma unroll
      for (int i = 0; i < 16; ++i) x[i] = basep[i*256 + tid];  // plain, coalesced
      #pragma unroll
      for (int i = 0; i < 16; ++i) {
        const int widx = i*256 + tid;       // [0,4096)
        const int bb = widx >> 10, j = widx & 1023;
        sA1[bb*3072 + 3*j + 0] = (unsigned short)(x[i]);
        sA1[bb*3072 + 3*j + 1] = (unsigned short)(x[i] >> 16);
        sA1[bb*3072 + 3*j + 2] = (unsigned short)(x[i] >> 32);
      }
      __syncthreads();
      const int ks = lane, isub = wv;
      float acc[3][4] = {};
      for (int ip = 0; ip < 12; ++ip) {
        const int k = ks + 64*(isub + 4*ip);
        float xv[4];
        #pragma unroll
        for (int bb = 0; bb < 4; ++bb) xv[bb] = b2f(sA1[bb*3072 + k]);
        #pragma unroll
        for (int c = 0; c < 3; ++c) {
          const float w = sV1[c*3072 + k];
          acc[c][0] += w*xv[0]; acc[c][1] += w*xv[1]; acc[c][2] += w*xv[2]; acc[c][3] += w*xv[3];
        }
      }
      #pragma unroll
      for (int c = 0; c < 3; ++c)
        #pragma unroll
        for (int bb = 0; bb < 4; ++bb) {
          const float v = wsum(acc[c][bb]);
          if (lane == 0) sRed[isub*12 + c*4 + bb] = v;
        }
      __syncthreads();
      if (tid < 4) {
        const int bb = tid;
        float v[3];
        #pragma unroll
        for (int c = 0; c < 3; ++c) {
          float s = sRed[c*4+bb] + sRed[12 + c*4+bb] + sRed[24 + c*4+bb] + sRed[36 + c*4+bb];
          v[c] = geluf(s + b1[g*3 + c]);
        }
        st64(tg_if + (size_t)t*1024 + g*4 + bb, pk3t(v[0], v[1], v[2], tagp));
      }
      vm0();
      __syncthreads();
      if (tid == 0) stflag(flg + FTG + g, t + 1);
    }

    // ================= P3: x2 EMA, cb, u slice =================
    {
      while (ldflag(flg + FTG + tid) < t + 1) __builtin_amdgcn_s_sleep(1);
      __syncthreads();
      const u64* pm = tg_if + (size_t)t*1024 + lane*16 + wv;
      u64 w4[4];
      #pragma unroll
      for (int qq = 0; qq < 4; ++qq) w4[qq] = pm[qq*4];
      float tv[12];
      #pragma unroll
      for (int qq = 0; qq < 4; ++qq) {
        tv[qq*3+0] = b2f((unsigned short)(w4[qq]));
        tv[qq*3+1] = b2f((unsigned short)(w4[qq] >> 16));
        tv[qq*3+2] = b2f((unsigned short)(w4[qq] >> 32));
      }
      const int xb = wv*768 + lane*12;
      float xv2[12];
      float ssqT = 0.f, ssqX = 0.f;
      #pragma unroll
      for (int i = 0; i < 12; ++i) {
        float xx = sX2[xb + i];
        const float tt = tv[i];
        #pragma unroll
        for (int rr = 0; rr < 10; ++rr) xx = 0.5f*xx + 0.5f*tt;
        sX2[xb + i] = xx; xv2[i] = xx;
        ssqT += tt*tt; ssqX += xx*xx;
      }
      ssqT = wsum(ssqT); ssqX = wsum(ssqX);
      const float invT = 1.0f / fmaxf(sqrtf(ssqT), 1e-12f);
      const float invX = 1.0f / fmaxf(sqrtf(ssqX), 1e-12f);
      #pragma unroll
      for (int i = 0; i < 12; ++i) sX[xb + i] = 0.5f*(tv[i]*invT + xv2[i]*invX);
      __syncthreads();
      const int ks = lane, isub = wv;
      float acc[3][4] = {};
      #pragma unroll
      for (int ip = 0; ip < 3; ++ip) {
        const int k = ks + 64*(isub + 4*ip);
        float xv[4];
        #pragma unroll
        for (int bb = 0; bb < 4; ++bb) xv[bb] = sX[bb*768 + k];
        #pragma unroll
        for (int c = 0; c < 3; ++c) {
          const float w = sW1[c*768 + k];
          acc[c][0] += w*xv[0]; acc[c][1] += w*xv[1]; acc[c][2] += w*xv[2]; acc[c][3] += w*xv[3];
        }
      }
      #pragma unroll
      for (int c = 0; c < 3; ++c)
        #pragma unroll
        for (int bb = 0; bb < 4; ++bb) {
          const float v = wsum(acc[c][bb]);
          if (lane == 0) sRed[isub*12 + c*4 + bb] = v;
        }
      __syncthreads();
      if (tid < 4) {
        const int bb = tid;
        float v[3];
        #pragma unroll
        for (int c = 0; c < 3; ++c) {
          float s = sRed[c*4+bb] + sRed[12 + c*4+bb] + sRed[24 + c*4+bb] + sRed[36 + c*4+bb];
          v[c] = geluf(s + c1[g*3 + c]);
        }
        st64(u_if + (size_t)t*1024 + g*4 + bb, pk3t(v[0], v[1], v[2], tagp));
      }
      vm0();
      __syncthreads();
      if (tid == 0) stflag(flg + FU + g, t + 1);
    }

    // ================= P4: cf/gv -> fused pre-LN slice =================
    {
      while (ldflag(flg + FU + tid) < t + 1) __builtin_amdgcn_s_sleep(1);
      __syncthreads();
      const u64* pm = u_if + (size_t)t*1024 + lane*16 + wv;
      u64 w4[4];
      #pragma unroll
      for (int qq = 0; qq < 4; ++qq) w4[qq] = pm[qq*4];
      const int xb = wv*768 + lane*12;
      #pragma unroll
      for (int qq = 0; qq < 4; ++qq) {
        sX[xb + qq*3 + 0] = b2f((unsigned short)(w4[qq]));
        sX[xb + qq*3 + 1] = b2f((unsigned short)(w4[qq] >> 16));
        sX[xb + qq*3 + 2] = b2f((unsigned short)(w4[qq] >> 32));
      }
      __syncthreads();
      const int ks = lane, isub = wv;
      float acc[6][4] = {};
      #pragma unroll
      for (int ip = 0; ip < 3; ++ip) {
        const int k = ks + 64*(isub + 4*ip);
        float xv[4];
        #pragma unroll
        for (int bb = 0; bb < 4; ++bb) xv[bb] = sX[bb*768 + k];
        #pragma unroll
        for (int c = 0; c < 6; ++c) {
          const float w = (c < 3) ? sW2[c*768 + k] : sW2G[(c-3)*768 + k];
          acc[c][0] += w*xv[0]; acc[c][1] += w*xv[1]; acc[c][2] += w*xv[2]; acc[c][3] += w*xv[3];
        }
      }
      #pragma unroll
      for (int c = 0; c < 6; ++c)
        #pragma unroll
        for (int bb = 0; bb < 4; ++bb) {
          const float v = wsum(acc[c][bb]);
          if (lane == 0) sRed[isub*24 + c*4 + bb] = v;
        }
      __syncthreads();
      if (tid < 4) {
        const int bb = tid;
        float pre3[3];
        #pragma unroll
        for (int c = 0; c < 3; ++c) {
          const int col = g*3 + c;
          float sc = sRed[c*4+bb] + sRed[24 + c*4+bb] + sRed[48 + c*4+bb] + sRed[72 + c*4+bb];
          const float cf = sc + c2[col];
          const int cc = c + 3;
          float sg = sRed[cc*4+bb] + sRed[24 + cc*4+bb] + sRed[48 + cc*4+bb] + sRed[72 + cc*4+bb];
          const float gv = sg + embWg[(size_t)(bb*256 + t)*768 + col] + gbias[col];
          const float gg = 1.0f / (1.0f + expf(-gv));
          const float em = emb_all[(size_t)(bb*256 + t)*768 + col];
          pre3[c] = gg*(cf + 0.4f*sTf[c*4 + bb]) + (1.0f - gg)*em;
        }
        st64(pre_if + (size_t)t*1024 + g*4 + bb, pk3t(pre3[0], pre3[1], pre3[2], tagp));
      }
      vm0();
      __syncthreads();
      if (tid == 0) stflag(flg + FPRE + g, t + 1);
    }
  }
}

// ---------------------------------------------------------------------------
// host
// ---------------------------------------------------------------------------
static void launch_gemm(const float* A, const void* B, float* C, const float* bias,
                        int M, int N, int bmode, hipStream_t st)
{
  const int ntiles = (N + 63) / 64;
  const int q = ntiles / 8, r = ntiles % 8;
  const int mtiles = M / 64;
  const int smax = (q + (r ? 1 : 0)) * mtiles;
  dim3 grid(8, smax);
  if (bmode == 0) gemm_kernel<0><<<grid, 256, 0, st>>>(A, B, C, bias, M, N, q, r);
  else            gemm_kernel<1><<<grid, 256, 0, st>>>(A, B, C, bias, M, N, q, r);
}

extern "C" void kernel_launch(void* const* d_in, const int* in_sizes, int n_in,
                              void* d_out, int out_size, void* d_ws, size_t ws_size,
                              hipStream_t stream)
{
  const int*   tok   = (const int*)d_in[0];
  const float* emb   = (const float*)d_in[1];
  const float* V0    = (const float*)d_in[2];
  const float* b0    = (const float*)d_in[3];
  const float* V1    = (const float*)d_in[4];
  const float* b1    = (const float*)d_in[5];
  const float* W1    = (const float*)d_in[6];
  const float* c1    = (const float*)d_in[7];
  const float* W2    = (const float*)d_in[8];
  const float* c2    = (const float*)d_in[9];
  const float* Wg    = (const float*)d_in[10];
  const float* bg    = (const float*)d_in[11];
  const float* Wt    = (const float*)d_in[12];
  const float* gamma = (const float*)d_in[13];
  const float* beta  = (const float*)d_in[14];
  const float* Wl    = (const float*)d_in[15];
  const float* Rw    = (const float*)d_in[16];

  float* outf = (float*)d_out;
  // scratch carved from d_out (all consumed before the final GEMM overwrites)
  float* emb_all = outf + 0;                    //  786432
  float* RV0     = outf + 786432;               // 2359296
  float* RWt     = outf + 3145728;              //  589824
  float* W2G     = outf + 3735552;              //  589824
  float* embV0   = outf + 4325376;              // 3145728
  float* embWg   = outf + 7471104;              //  786432
  float* gbias   = outf + 8257536;              //    1024
  unsigned short* V0T  = (unsigned short*)(outf + 8258560);   // 2359296 el
  unsigned short* WtT  = (unsigned short*)(outf + 9438208);   //  589824 el
  unsigned short* WgTT = (unsigned short*)(outf + 9733120);   //  589824 el
  unsigned short* WgBT = (unsigned short*)(outf + 10028032);  //  589824 el
  u64* a1_if  = (u64*)(outf + 10322944);  // 257*4096 u64 -> 2105344 f
  u64* tg_if  = (u64*)(outf + 12428288);  // 257*1024 u64 ->  526336 f
  u64* u_if   = (u64*)(outf + 12954624);
  u64* pre_if = (u64*)(outf + 13480960);
  int* flg    = (int*)(outf + 14007296);  // 1024 ints
                                          // end 14008320 < 51463168

  float* h_all = (float*)d_ws;                                // 786432 f32
  unsigned short* WlT = (unsigned short*)((char*)d_ws + 786432*4);
  const bool bigws = ws_size >= (size_t)(786432*4) + (size_t)38597376*2 + 256;

  hipMemsetAsync(flg, 0, 1024 * sizeof(int), stream);

  // transposed bf16 copies of GEMM B operands
  transpose_f2b<<<dim3(96, 24),   256, 0, stream>>>(V0, V0T, 3072, 0);
  transpose_f2b<<<dim3(24, 24),   256, 0, stream>>>(Wt, WtT, 768, 0);
  transpose_f2b<<<dim3(24, 24),   256, 0, stream>>>(Wg, WgTT, 768, 0);
  transpose_f2b<<<dim3(24, 24),   256, 0, stream>>>(Wg, WgBT, 768, 768);
  if (bigws)
    transpose_f2b<<<dim3(1572, 24), 256, 0, stream>>>(Wl, WlT, 50257, 0);

  embed_kernel<<<1024, 256, 0, stream>>>(tok, emb, emb_all);
  gbias_kernel<<<3, 256, 0, stream>>>(c2, Wg, gbias);

  // fused-weight + per-token precompute GEMMs (bf16 MFMA, fp32 out)
  launch_gemm(Rw,      V0T,  RV0,   nullptr, 768,  3072, 0, stream);
  launch_gemm(Rw,      WtT,  RWt,   nullptr, 768,  768,  0, stream);
  launch_gemm(W2,      WgBT, W2G,   nullptr, 768,  768,  0, stream);
  launch_gemm(emb_all, V0T,  embV0, b0,      1024, 3072, 0, stream);
  launch_gemm(emb_all, WgTT, embWg, bg,      1024, 768,  0, stream);

  // the sequential part
  recur_kernel<<<256, 256, 0, stream>>>(
      RV0, RWt, W1, W2, W2G, V1, embV0, embWg, gbias, emb_all,
      b1, c1, c2, gamma, beta, h_all,
      a1_if, tg_if, u_if, pre_if, flg);

  // deferred lm_head: logits[b*256+t][v] = h_all @ Wl
  if (bigws) launch_gemm(h_all, WlT, outf, nullptr, 1024, 50257, 0, stream);
  else       launch_gemm(h_all, Wl,  outf, nullptr, 1024, 50257, 1, stream);
}

// Round 7
// 10983.157 us; speedup vs baseline: 3.4957x; 1.0002x over previous
//
#include <hip/hip_runtime.h>

// ============================================================================
// AgnisV5: sequential recurrence (4-phase persistent kernel, weights in LDS)
//          + deferred batched lm_head GEMM (bf16 MFMA).
//
// Round-6 change: FLAG-GATED PLAIN-LOAD TRANSPORT (implicit per-XCD L2 fanout).
// R3's floor was sc1 read BW: 256 consumers x full payload ~14MB/step at
// ~400GB/s ~= the 39us/step. Now transport buffers are WRITE-ONCE (indexed by
// step t, no reuse within a dispatch), so consumers may read them with PLAIN
// loads: first WG per XCD misses L2 -> pulls fresh line from IF$; remaining 31
// WGs hit local L2. Release protocol (all primitives proven in R2/R3):
//   producer: st64(sc1) payload -> s_waitcnt vmcnt(0) -> __syncthreads
//             -> tid==0 st32(sc1) per-WG flag = t+1   (flags memset 0/launch)
//   consumer: thread tid sc1-polls flag[tid] >= want -> __syncthreads
//             -> plain vector loads of payload.
// Within-dispatch staleness impossible (write-once); across dispatches the
// L1/L2 are invalidated at dispatch boundaries (relied on since R1 for the
// GEMM->recur weight flow); replay values are bit-identical regardless.
// P4 emits the fused pre-LN slice sigma(gv)*(cf+0.4tf)+(1-sigma)*emb (tf kept
// in LDS), so the h-phase gathers 4 words/thread.
// ============================================================================

typedef __attribute__((ext_vector_type(8))) short short8;
typedef __attribute__((ext_vector_type(4))) float f32x4;
typedef unsigned long long u64;

__device__ __forceinline__ unsigned short f2b(float f){
  unsigned int u = __builtin_bit_cast(unsigned int, f);
  u += 0x7fffu + ((u >> 16) & 1u);
  return (unsigned short)(u >> 16);
}
__device__ __forceinline__ float b2f(unsigned short v){
  return __builtin_bit_cast(float, ((unsigned int)v) << 16);
}
__device__ __forceinline__ float geluf(float x){
  return 0.5f * x * (1.0f + erff(x * 0.70710678118654752440f));
}
__device__ __forceinline__ float wsum(float v){
  #pragma unroll
  for (int o = 32; o; o >>= 1) v += __shfl_xor(v, o, 64);
  return v;
}
__device__ __forceinline__ u64 pk3t(float a, float b, float c, unsigned tag){
  return (u64)f2b(a) | ((u64)f2b(b) << 16) | ((u64)f2b(c) << 32) | ((u64)(tag & 0xffffu) << 48);
}
// sc1 (IF$-coherent) accessors — the only cross-XCD-visible ops we use
__device__ __forceinline__ void st64(u64* p, u64 v){
  __hip_atomic_store(p, v, __ATOMIC_RELAXED, __HIP_MEMORY_SCOPE_AGENT);
}
__device__ __forceinline__ void stflag(int* p, int v){
  __hip_atomic_store(p, v, __ATOMIC_RELAXED, __HIP_MEMORY_SCOPE_AGENT);
}
__device__ __forceinline__ int ldflag(const int* p){
  return __hip_atomic_load(p, __ATOMIC_RELAXED, __HIP_MEMORY_SCOPE_AGENT);
}
__device__ __forceinline__ void vm0(){ asm volatile("s_waitcnt vmcnt(0)" ::: "memory"); }

// flag array indices
#define FA1  0
#define FTG  256
#define FU   512
#define FPRE 768

// ---------------------------------------------------------------------------
// transpose + f32->bf16 : src [768, N] (rows offset by rowoff) -> dst [N, 768]
// ---------------------------------------------------------------------------
__global__ __launch_bounds__(256) void transpose_f2b(
    const float* __restrict__ src, unsigned short* __restrict__ dst,
    int N, int rowoff)
{
  __shared__ unsigned short tile[32][33];
  const int nb = blockIdx.x * 32, kb = blockIdx.y * 32;
  const int tx = threadIdx.x & 31, ty = threadIdx.x >> 5;
  #pragma unroll
  for (int i = 0; i < 4; ++i) {
    int k = kb + ty + 8*i, n = nb + tx;
    unsigned short v = 0;
    if (n < N) v = f2b(src[(size_t)(rowoff + k)*N + n]);
    tile[ty + 8*i][tx] = v;
  }
  __syncthreads();
  #pragma unroll
  for (int i = 0; i < 4; ++i) {
    int n = nb + ty + 8*i;
    if (n < N) dst[(size_t)n*768 + kb + tx] = tile[tx][ty + 8*i];
  }
}

// ---------------------------------------------------------------------------
// embedding gather + L2 normalize : emb_all[b*256+t][768]
// ---------------------------------------------------------------------------
__global__ __launch_bounds__(256) void embed_kernel(
    const int* __restrict__ tok, const float* __restrict__ emb,
    float* __restrict__ emb_all)
{
  const int row = blockIdx.x, tid = threadIdx.x;
  const int id = tok[row];
  const float* e = emb + (size_t)id * 768;
  float v0 = e[tid], v1 = e[tid+256], v2 = e[tid+512];
  float ssq = wsum(v0*v0 + v1*v1 + v2*v2);
  __shared__ float red[4];
  if ((tid & 63) == 0) red[tid >> 6] = ssq;
  __syncthreads();
  float inv = 1.0f / fmaxf(sqrtf(red[0]+red[1]+red[2]+red[3]), 1e-12f);
  float* o = emb_all + (size_t)row * 768;
  o[tid] = v0*inv; o[tid+256] = v1*inv; o[tid+512] = v2*inv;
}

// gbias[c] = sum_k c2[k] * Wg[768+k][c]
__global__ void gbias_kernel(const float* __restrict__ c2,
                             const float* __restrict__ Wg,
                             float* __restrict__ gbias)
{
  int c = blockIdx.x * 256 + threadIdx.x;
  if (c >= 768) return;
  float s = 0.f;
  for (int k = 0; k < 768; ++k) s += c2[k] * Wg[(size_t)(768 + k)*768 + c];
  gbias[c] = s;
}

// ---------------------------------------------------------------------------
// GEMM: C[M,N] = A[M,768](f32, bf16-cast) @ B + bias
//   BMODE 0: B = BT bf16 [N,768] (transposed)   BMODE 1: B = f32 [768,N]
// ---------------------------------------------------------------------------
template<int BMODE>
__global__ __launch_bounds__(256) void gemm_kernel(
    const float* __restrict__ A, const void* __restrict__ Bp,
    float* __restrict__ C, const float* __restrict__ bias,
    int M, int N, int q, int r)
{
  const int x = blockIdx.x;
  const int s = blockIdx.y;
  const int mtiles = M >> 6;
  const int cnt_x = q + (x < r ? 1 : 0);
  if (s >= cnt_x * mtiles) return;
  const int off_x = x*q + (x < r ? x : r);
  const int nt = off_x + s / mtiles;
  const int mt = s % mtiles;
  const int m0 = mt << 6, n0 = nt << 6;
  const int w = threadIdx.x >> 6, l = threadIdx.x & 63;
  const int lrow = l & 15, lk8 = (l >> 4) << 3;
  const int arow = m0 + w*16 + lrow;
  f32x4 acc[4] = {f32x4{0,0,0,0}, f32x4{0,0,0,0}, f32x4{0,0,0,0}, f32x4{0,0,0,0}};
  const unsigned short* BT = (const unsigned short*)Bp;
  const float* Bf = (const float*)Bp;

  for (int kk = 0; kk < 768; kk += 32) {
    const float4* ap = (const float4*)(A + (size_t)arow*768 + kk + lk8);
    float4 a0 = ap[0], a1 = ap[1];
    short8 af;
    af[0]=(short)f2b(a0.x); af[1]=(short)f2b(a0.y); af[2]=(short)f2b(a0.z); af[3]=(short)f2b(a0.w);
    af[4]=(short)f2b(a1.x); af[5]=(short)f2b(a1.y); af[6]=(short)f2b(a1.z); af[7]=(short)f2b(a1.w);
    #pragma unroll
    for (int ss = 0; ss < 4; ++ss) {
      const int col = n0 + ss*16 + lrow;
      short8 bf;
      if (BMODE == 0) {
        if (col < N) {
          uint4 raw = *(const uint4*)(BT + (size_t)col*768 + kk + lk8);
          bf = __builtin_bit_cast(short8, raw);
        } else {
          bf = short8{0,0,0,0,0,0,0,0};
        }
      } else {
        #pragma unroll
        for (int j = 0; j < 8; ++j) {
          float v = (col < N) ? Bf[(size_t)(kk + lk8 + j)*N + col] : 0.f;
          bf[j] = (short)f2b(v);
        }
      }
      acc[ss] = __builtin_amdgcn_mfma_f32_16x16x32_bf16(af, bf, acc[ss], 0, 0, 0);
    }
  }
  const int rbase = m0 + w*16 + ((l >> 4) << 2);
  #pragma unroll
  for (int ss = 0; ss < 4; ++ss) {
    const int col = n0 + ss*16 + lrow;
    if (col < N) {
      const float badd = bias ? bias[col] : 0.f;
      #pragma unroll
      for (int rr = 0; rr < 4; ++rr)
        C[(size_t)(rbase + rr)*N + col] = acc[ss][rr] + badd;
    }
  }
}

// ---------------------------------------------------------------------------
// Persistent recurrent kernel: 256 WGs (1/CU), 256 threads.
// WG g owns cols [g*12,+12) of RV0 and [g*3,+3) of V1/W1/W2/W2G/RWt in LDS.
// Transport: write-once step-indexed buffers + per-WG flags (see header).
//   a1_if : [257 t][4 bb][1024 w] u64, word j = cols 3j..3j+2
//   tg/u/pre_if : [257 t][1024 w] u64, word = G*4+bb -> cols G*3..G*3+2
// ---------------------------------------------------------------------------
__global__ __launch_bounds__(256) void recur_kernel(
    const float* __restrict__ RV0, const float* __restrict__ RWt,
    const float* __restrict__ W1,  const float* __restrict__ W2,
    const float* __restrict__ W2G, const float* __restrict__ V1,
    const float* __restrict__ embV0, const float* __restrict__ embWg,
    const float* __restrict__ gbias, const float* __restrict__ emb_all,
    const float* __restrict__ b1, const float* __restrict__ c1,
    const float* __restrict__ c2, const float* __restrict__ gam,
    const float* __restrict__ bet, float* __restrict__ h_all,
    u64* __restrict__ a1_if, u64* __restrict__ tg_if,
    u64* __restrict__ u_if,  u64* __restrict__ pre_if,
    int* __restrict__ flg)
{
  __shared__ float sRV0[12*768];        // 36864 B
  __shared__ float sV1[3*3072];         // 36864 B
  __shared__ float sW1[3*768];
  __shared__ float sW2[3*768];
  __shared__ float sW2G[3*768];
  __shared__ float sRWt[3*768];         // 4 x 9216 B
  __shared__ float sX[4*768];           // 12288 B
  __shared__ float sX2[4*768];          // 12288 B
  __shared__ unsigned short sA1[4*3072];// 24576 B
  __shared__ float sRed[240];           // 960 B
  __shared__ float sTf[16];             // 64 B   -- total 160768 B

  const int g = blockIdx.x, tid = threadIdx.x;
  const int wv = tid >> 6, lane = tid & 63;

  // ---- load weight slices into LDS ----
  for (int i = tid; i < 12*768; i += 256) {
    int k = i / 12, c = i - k*12;
    sRV0[c*768 + k] = RV0[(size_t)k*3072 + g*12 + c];
  }
  for (int i = tid; i < 3*3072; i += 256) {
    int k = i / 3, c = i - k*3;
    sV1[c*3072 + k] = V1[(size_t)k*768 + g*3 + c];
  }
  for (int i = tid; i < 3*768; i += 256) {
    int k = i / 3, c = i - k*3;
    const int gc = g*3 + c;
    sW1[c*768 + k]  = W1[(size_t)k*768 + gc];
    sW2[c*768 + k]  = W2[(size_t)k*768 + gc];
    sW2G[c*768 + k] = W2G[(size_t)k*768 + gc];
    sRWt[c*768 + k] = RWt[(size_t)k*768 + gc];
  }
  for (int i = tid; i < 4*768; i += 256) sX2[i] = 0.f;
  __syncthreads();

  for (int t = 0; t <= 256; ++t) {
    // ================= h_{t-1} from fused pre-LN words =================
    if (t == 0) {
      for (int i = tid; i < 4*768; i += 256) sX[i] = 0.f;
    } else {
      while (ldflag(flg + FPRE + tid) < t) __builtin_amdgcn_s_sleep(1);
      __syncthreads();
      const u64* pm = pre_if + (size_t)(t-1)*1024 + lane*16 + wv;
      u64 w4[4];
      #pragma unroll
      for (int qq = 0; qq < 4; ++qq) w4[qq] = pm[qq*4];   // plain, L2-served
      float pre[12];
      #pragma unroll
      for (int qq = 0; qq < 4; ++qq) {
        pre[qq*3+0] = b2f((unsigned short)(w4[qq]));
        pre[qq*3+1] = b2f((unsigned short)(w4[qq] >> 16));
        pre[qq*3+2] = b2f((unsigned short)(w4[qq] >> 32));
      }
      float s1 = 0.f;
      #pragma unroll
      for (int i = 0; i < 12; ++i) s1 += pre[i];
      s1 = wsum(s1);
      const float mean = s1 * (1.0f/768.0f);
      float s2 = 0.f;
      #pragma unroll
      for (int i = 0; i < 12; ++i) { const float d = pre[i] - mean; s2 += d*d; }
      s2 = wsum(s2);
      const float rstd = 1.0f / sqrtf(s2*(1.0f/768.0f) + 1e-5f);
      const int k0 = lane*12;
      float hv[12];
      #pragma unroll
      for (int i = 0; i < 12; ++i) {
        hv[i] = (pre[i] - mean)*rstd*gam[k0+i] + bet[k0+i];
        sX[wv*768 + k0 + i] = hv[i];
      }
      if (g == 0) {
        float* hp = h_all + (size_t)(wv*256 + t - 1)*768 + k0;
        #pragma unroll
        for (int i = 0; i < 12; ++i) hp[i] = hv[i];
      }
    }
    __syncthreads();
    if (t == 256) break;
    const unsigned tagp = (unsigned)(t + 1);

    // ================= P1: a1 slice (12 cols), tf slice (LDS stash) ========
    {
      const int cg = tid >> 6, ks = tid & 63;
      float acc[4][4] = {};
      for (int i = 0; i < 12; ++i) {
        const int k = ks + 64*i;
        const float x0 = sX[k], x1 = sX[768+k], x2v = sX[1536+k], x3 = sX[2304+k];
        #pragma unroll
        for (int j = 0; j < 4; ++j) {
          float w;
          if (cg < 3) w = sRV0[(cg*4 + j)*768 + k];
          else        w = (j < 3) ? sRWt[j*768 + k] : 0.f;
          acc[j][0] += w*x0; acc[j][1] += w*x1; acc[j][2] += w*x2v; acc[j][3] += w*x3;
        }
      }
      #pragma unroll
      for (int j = 0; j < 4; ++j)
        #pragma unroll
        for (int bb = 0; bb < 4; ++bb) {
          const float v = wsum(acc[j][bb]);
          if (lane == 0) sRed[cg*16 + j*4 + bb] = v;
        }
      __syncthreads();
      if (tid < 16) {               // 16 a1 words: bb = tid&3, w = tid>>2
        const int bb = tid & 3, w = tid >> 2;
        float v[3];
        #pragma unroll
        for (int s = 0; s < 3; ++s) {
          const int c = w*3 + s;    // 0..11
          const float raw = sRed[(c >> 2)*16 + (c & 3)*4 + bb];
          v[s] = geluf(embV0[(size_t)(bb*256 + t)*3072 + g*12 + c] + 0.4f*raw);
        }
        st64(a1_if + (size_t)t*4096 + bb*1024 + g*4 + w, pk3t(v[0], v[1], v[2], tagp));
      } else if (tid < 20) {        // stash tf slice for P4's fused pre
        const int bb = tid - 16;
        sTf[bb]     = sRed[48 + bb];
        sTf[4 + bb] = sRed[52 + bb];
        sTf[8 + bb] = sRed[56 + bb];
      }
      vm0();
      __syncthreads();
      if (tid == 0) stflag(flg + FA1 + g, t + 1);
    }

    // ================= P2: target slice =================
    {
      while (ldflag(flg + FA1 + tid) < t + 1) __builtin_amdgcn_s_sleep(1);
      __syncthreads();
      const u64* basep = a1_if + (size_t)t*4096;
      u64 x[16];
      #pragma unroll
      for (int i = 0; i < 16; ++i) x[i] = basep[i*256 + tid];  // plain, coalesced
      #pragma unroll
      for (int i = 0; i < 16; ++i) {
        const int widx = i*256 + tid;       // [0,4096)
        const int bb = widx >> 10, j = widx & 1023;
        sA1[bb*3072 + 3*j + 0] = (unsigned short)(x[i]);
        sA1[bb*3072 + 3*j + 1] = (unsigned short)(x[i] >> 16);
        sA1[bb*3072 + 3*j + 2] = (unsigned short)(x[i] >> 32);
      }
      __syncthreads();
      const int ks = lane, isub = wv;
      float acc[3][4] = {};
      for (int ip = 0; ip < 12; ++ip) {
        const int k = ks + 64*(isub + 4*ip);
        float xv[4];
        #pragma unroll
        for (int bb = 0; bb < 4; ++bb) xv[bb] = b2f(sA1[bb*3072 + k]);
        #pragma unroll
        for (int c = 0; c < 3; ++c) {
          const float w = sV1[c*3072 + k];
          acc[c][0] += w*xv[0]; acc[c][1] += w*xv[1]; acc[c][2] += w*xv[2]; acc[c][3] += w*xv[3];
        }
      }
      #pragma unroll
      for (int c = 0; c < 3; ++c)
        #pragma unroll
        for (int bb = 0; bb < 4; ++bb) {
          const float v = wsum(acc[c][bb]);
          if (lane == 0) sRed[isub*12 + c*4 + bb] = v;
        }
      __syncthreads();
      if (tid < 4) {
        const int bb = tid;
        float v[3];
        #pragma unroll
        for (int c = 0; c < 3; ++c) {
          float s = sRed[c*4+bb] + sRed[12 + c*4+bb] + sRed[24 + c*4+bb] + sRed[36 + c*4+bb];
          v[c] = geluf(s + b1[g*3 + c]);
        }
        st64(tg_if + (size_t)t*1024 + g*4 + bb, pk3t(v[0], v[1], v[2], tagp));
      }
      vm0();
      __syncthreads();
      if (tid == 0) stflag(flg + FTG + g, t + 1);
    }

    // ================= P3: x2 EMA, cb, u slice =================
    {
      while (ldflag(flg + FTG + tid) < t + 1) __builtin_amdgcn_s_sleep(1);
      __syncthreads();
      const u64* pm = tg_if + (size_t)t*1024 + lane*16 + wv;
      u64 w4[4];
      #pragma unroll
      for (int qq = 0; qq < 4; ++qq) w4[qq] = pm[qq*4];
      float tv[12];
      #pragma unroll
      for (int qq = 0; qq < 4; ++qq) {
        tv[qq*3+0] = b2f((unsigned short)(w4[qq]));
        tv[qq*3+1] = b2f((unsigned short)(w4[qq] >> 16));
        tv[qq*3+2] = b2f((unsigned short)(w4[qq] >> 32));
      }
      const int xb = wv*768 + lane*12;
      float xv2[12];
      float ssqT = 0.f, ssqX = 0.f;
      #pragma unroll
      for (int i = 0; i < 12; ++i) {
        float xx = sX2[xb + i];
        const float tt = tv[i];
        #pragma unroll
        for (int rr = 0; rr < 10; ++rr) xx = 0.5f*xx + 0.5f*tt;
        sX2[xb + i] = xx; xv2[i] = xx;
        ssqT += tt*tt; ssqX += xx*xx;
      }
      ssqT = wsum(ssqT); ssqX = wsum(ssqX);
      const float invT = 1.0f / fmaxf(sqrtf(ssqT), 1e-12f);
      const float invX = 1.0f / fmaxf(sqrtf(ssqX), 1e-12f);
      #pragma unroll
      for (int i = 0; i < 12; ++i) sX[xb + i] = 0.5f*(tv[i]*invT + xv2[i]*invX);
      __syncthreads();
      const int ks = lane, isub = wv;
      float acc[3][4] = {};
      #pragma unroll
      for (int ip = 0; ip < 3; ++ip) {
        const int k = ks + 64*(isub + 4*ip);
        float xv[4];
        #pragma unroll
        for (int bb = 0; bb < 4; ++bb) xv[bb] = sX[bb*768 + k];
        #pragma unroll
        for (int c = 0; c < 3; ++c) {
          const float w = sW1[c*768 + k];
          acc[c][0] += w*xv[0]; acc[c][1] += w*xv[1]; acc[c][2] += w*xv[2]; acc[c][3] += w*xv[3];
        }
      }
      #pragma unroll
      for (int c = 0; c < 3; ++c)
        #pragma unroll
        for (int bb = 0; bb < 4; ++bb) {
          const float v = wsum(acc[c][bb]);
          if (lane == 0) sRed[isub*12 + c*4 + bb] = v;
        }
      __syncthreads();
      if (tid < 4) {
        const int bb = tid;
        float v[3];
        #pragma unroll
        for (int c = 0; c < 3; ++c) {
          float s = sRed[c*4+bb] + sRed[12 + c*4+bb] + sRed[24 + c*4+bb] + sRed[36 + c*4+bb];
          v[c] = geluf(s + c1[g*3 + c]);
        }
        st64(u_if + (size_t)t*1024 + g*4 + bb, pk3t(v[0], v[1], v[2], tagp));
      }
      vm0();
      __syncthreads();
      if (tid == 0) stflag(flg + FU + g, t + 1);
    }

    // ================= P4: cf/gv -> fused pre-LN slice =================
    {
      while (ldflag(flg + FU + tid) < t + 1) __builtin_amdgcn_s_sleep(1);
      __syncthreads();
      const u64* pm = u_if + (size_t)t*1024 + lane*16 + wv;
      u64 w4[4];
      #pragma unroll
      for (int qq = 0; qq < 4; ++qq) w4[qq] = pm[qq*4];
      const int xb = wv*768 + lane*12;
      #pragma unroll
      for (int qq = 0; qq < 4; ++qq) {
        sX[xb + qq*3 + 0] = b2f((unsigned short)(w4[qq]));
        sX[xb + qq*3 + 1] = b2f((unsigned short)(w4[qq] >> 16));
        sX[xb + qq*3 + 2] = b2f((unsigned short)(w4[qq] >> 32));
      }
      __syncthreads();
      const int ks = lane, isub = wv;
      float acc[6][4] = {};
      #pragma unroll
      for (int ip = 0; ip < 3; ++ip) {
        const int k = ks + 64*(isub + 4*ip);
        float xv[4];
        #pragma unroll
        for (int bb = 0; bb < 4; ++bb) xv[bb] = sX[bb*768 + k];
        #pragma unroll
        for (int c = 0; c < 6; ++c) {
          const float w = (c < 3) ? sW2[c*768 + k] : sW2G[(c-3)*768 + k];
          acc[c][0] += w*xv[0]; acc[c][1] += w*xv[1]; acc[c][2] += w*xv[2]; acc[c][3] += w*xv[3];
        }
      }
      #pragma unroll
      for (int c = 0; c < 6; ++c)
        #pragma unroll
        for (int bb = 0; bb < 4; ++bb) {
          const float v = wsum(acc[c][bb]);
          if (lane == 0) sRed[isub*24 + c*4 + bb] = v;
        }
      __syncthreads();
      if (tid < 4) {
        const int bb = tid;
        float pre3[3];
        #pragma unroll
        for (int c = 0; c < 3; ++c) {
          const int col = g*3 + c;
          float sc = sRed[c*4+bb] + sRed[24 + c*4+bb] + sRed[48 + c*4+bb] + sRed[72 + c*4+bb];
          const float cf = sc + c2[col];
          const int cc = c + 3;
          float sg = sRed[cc*4+bb] + sRed[24 + cc*4+bb] + sRed[48 + cc*4+bb] + sRed[72 + cc*4+bb];
          const float gv = sg + embWg[(size_t)(bb*256 + t)*768 + col] + gbias[col];
          const float gg = 1.0f / (1.0f + expf(-gv));
          const float em = emb_all[(size_t)(bb*256 + t)*768 + col];
          pre3[c] = gg*(cf + 0.4f*sTf[c*4 + bb]) + (1.0f - gg)*em;
        }
        st64(pre_if + (size_t)t*1024 + g*4 + bb, pk3t(pre3[0], pre3[1], pre3[2], tagp));
      }
      vm0();
      __syncthreads();
      if (tid == 0) stflag(flg + FPRE + g, t + 1);
    }
  }
}

// ---------------------------------------------------------------------------
// host
// ---------------------------------------------------------------------------
static void launch_gemm(const float* A, const void* B, float* C, const float* bias,
                        int M, int N, int bmode, hipStream_t st)
{
  const int ntiles = (N + 63) / 64;
  const int q = ntiles / 8, r = ntiles % 8;
  const int mtiles = M / 64;
  const int smax = (q + (r ? 1 : 0)) * mtiles;
  dim3 grid(8, smax);
  if (bmode == 0) gemm_kernel<0><<<grid, 256, 0, st>>>(A, B, C, bias, M, N, q, r);
  else            gemm_kernel<1><<<grid, 256, 0, st>>>(A, B, C, bias, M, N, q, r);
}

extern "C" void kernel_launch(void* const* d_in, const int* in_sizes, int n_in,
                              void* d_out, int out_size, void* d_ws, size_t ws_size,
                              hipStream_t stream)
{
  const int*   tok   = (const int*)d_in[0];
  const float* emb   = (const float*)d_in[1];
  const float* V0    = (const float*)d_in[2];
  const float* b0    = (const float*)d_in[3];
  const float* V1    = (const float*)d_in[4];
  const float* b1    = (const float*)d_in[5];
  const float* W1    = (const float*)d_in[6];
  const float* c1    = (const float*)d_in[7];
  const float* W2    = (const float*)d_in[8];
  const float* c2    = (const float*)d_in[9];
  const float* Wg    = (const float*)d_in[10];
  const float* bg    = (const float*)d_in[11];
  const float* Wt    = (const float*)d_in[12];
  const float* gamma = (const float*)d_in[13];
  const float* beta  = (const float*)d_in[14];
  const float* Wl    = (const float*)d_in[15];
  const float* Rw    = (const float*)d_in[16];

  float* outf = (float*)d_out;
  // scratch carved from d_out (all consumed before the final GEMM overwrites)
  float* emb_all = outf + 0;                    //  786432
  float* RV0     = outf + 786432;               // 2359296
  float* RWt     = outf + 3145728;              //  589824
  float* W2G     = outf + 3735552;              //  589824
  float* embV0   = outf + 4325376;              // 3145728
  float* embWg   = outf + 7471104;              //  786432
  float* gbias   = outf + 8257536;              //    1024
  unsigned short* V0T  = (unsigned short*)(outf + 8258560);   // 2359296 el
  unsigned short* WtT  = (unsigned short*)(outf + 9438208);   //  589824 el
  unsigned short* WgTT = (unsigned short*)(outf + 9733120);   //  589824 el
  unsigned short* WgBT = (unsigned short*)(outf + 10028032);  //  589824 el
  u64* a1_if  = (u64*)(outf + 10322944);  // 257*4096 u64 -> 2105344 f
  u64* tg_if  = (u64*)(outf + 12428288);  // 257*1024 u64 ->  526336 f
  u64* u_if   = (u64*)(outf + 12954624);
  u64* pre_if = (u64*)(outf + 13480960);
  int* flg    = (int*)(outf + 14007296);  // 1024 ints
                                          // end 14008320 < 51463168

  float* h_all = (float*)d_ws;                                // 786432 f32
  unsigned short* WlT = (unsigned short*)((char*)d_ws + 786432*4);
  const bool bigws = ws_size >= (size_t)(786432*4) + (size_t)38597376*2 + 256;

  hipMemsetAsync(flg, 0, 1024 * sizeof(int), stream);

  // transposed bf16 copies of GEMM B operands
  transpose_f2b<<<dim3(96, 24),   256, 0, stream>>>(V0, V0T, 3072, 0);
  transpose_f2b<<<dim3(24, 24),   256, 0, stream>>>(Wt, WtT, 768, 0);
  transpose_f2b<<<dim3(24, 24),   256, 0, stream>>>(Wg, WgTT, 768, 0);
  transpose_f2b<<<dim3(24, 24),   256, 0, stream>>>(Wg, WgBT, 768, 768);
  if (bigws)
    transpose_f2b<<<dim3(1572, 24), 256, 0, stream>>>(Wl, WlT, 50257, 0);

  embed_kernel<<<1024, 256, 0, stream>>>(tok, emb, emb_all);
  gbias_kernel<<<3, 256, 0, stream>>>(c2, Wg, gbias);

  // fused-weight + per-token precompute GEMMs (bf16 MFMA, fp32 out)
  launch_gemm(Rw,      V0T,  RV0,   nullptr, 768,  3072, 0, stream);
  launch_gemm(Rw,      WtT,  RWt,   nullptr, 768,  768,  0, stream);
  launch_gemm(W2,      WgBT, W2G,   nullptr, 768,  768,  0, stream);
  launch_gemm(emb_all, V0T,  embV0, b0,      1024, 3072, 0, stream);
  launch_gemm(emb_all, WgTT, embWg, bg,      1024, 768,  0, stream);

  // the sequential part
  recur_kernel<<<256, 256, 0, stream>>>(
      RV0, RWt, W1, W2, W2G, V1, embV0, embWg, gbias, emb_all,
      b1, c1, c2, gamma, beta, h_all,
      a1_if, tg_if, u_if, pre_if, flg);

  // deferred lm_head: logits[b*256+t][v] = h_all @ Wl
  if (bigws) launch_gemm(h_all, WlT, outf, nullptr, 1024, 50257, 0, stream);
  else       launch_gemm(h_all, Wl,  outf, nullptr, 1024, 50257, 1, stream);
}

// Round 8
// 10394.415 us; speedup vs baseline: 3.6937x; 1.0566x over previous
//
#include <hip/hip_runtime.h>

// ============================================================================
// AgnisV5: sequential recurrence (4-phase persistent kernel, weights in LDS)
//          + deferred batched lm_head GEMM (bf16 MFMA).
//
// Round-7 change: 2-LEVEL FLAG AGGREGATION TREE (H3: poll-pressure test).
// Evidence R2/R3/R6: grid-wide sync costs ~9.6us/phase regardless of protocol
// or payload volume -> suspect contention: 65536 poller threads hammer the 16
// cache lines holding the per-WG flags, queuing the producers' flag stores
// behind poll traffic at the coherence point. Now:
//   level 0: producer WG g stores flag0[g] = t+1   (sc1, unchanged)
//   level 1: WGs 0..15 poll their group's 16 flag0s (16 threads, 1 line,
//            16 pollers -> uncontended), then store flag1[a] = t+1
//   consume: ALL WGs poll the 16 flag1 words with 16 threads (1 shared
//            read-only line, ~0.2 req/ns aggregate -> benign), __syncthreads,
//            then PLAIN payload loads (write-once step-indexed buffers,
//            per-XCD L2 fanout -- proven in R6, FETCH evidence).
// Payload path, producer release (st64 sc1 -> vmcnt(0) -> syncthreads ->
// flag0), numerics, and all buffer layouts are IDENTICAL to the passing R6.
// ============================================================================

typedef __attribute__((ext_vector_type(8))) short short8;
typedef __attribute__((ext_vector_type(4))) float f32x4;
typedef unsigned long long u64;

__device__ __forceinline__ unsigned short f2b(float f){
  unsigned int u = __builtin_bit_cast(unsigned int, f);
  u += 0x7fffu + ((u >> 16) & 1u);
  return (unsigned short)(u >> 16);
}
__device__ __forceinline__ float b2f(unsigned short v){
  return __builtin_bit_cast(float, ((unsigned int)v) << 16);
}
__device__ __forceinline__ float geluf(float x){
  return 0.5f * x * (1.0f + erff(x * 0.70710678118654752440f));
}
__device__ __forceinline__ float wsum(float v){
  #pragma unroll
  for (int o = 32; o; o >>= 1) v += __shfl_xor(v, o, 64);
  return v;
}
__device__ __forceinline__ u64 pk3t(float a, float b, float c, unsigned tag){
  return (u64)f2b(a) | ((u64)f2b(b) << 16) | ((u64)f2b(c) << 32) | ((u64)(tag & 0xffffu) << 48);
}
// sc1 (IF$-coherent) accessors — the only cross-XCD-visible ops we use
__device__ __forceinline__ void st64(u64* p, u64 v){
  __hip_atomic_store(p, v, __ATOMIC_RELAXED, __HIP_MEMORY_SCOPE_AGENT);
}
__device__ __forceinline__ void stflag(int* p, int v){
  __hip_atomic_store(p, v, __ATOMIC_RELAXED, __HIP_MEMORY_SCOPE_AGENT);
}
__device__ __forceinline__ int ldflag(const int* p){
  return __hip_atomic_load(p, __ATOMIC_RELAXED, __HIP_MEMORY_SCOPE_AGENT);
}
__device__ __forceinline__ void vm0(){ asm volatile("s_waitcnt vmcnt(0)" ::: "memory"); }

// flag0 (per-WG) indices
#define FA1  0
#define FTG  256
#define FU   512
#define FPRE 768
// flag1 (per-aggregator, 16 each, separate cache lines per phase)
#define F2A1  1024
#define F2TG  1088
#define F2U   1152
#define F2PRE 1216

// ---------------------------------------------------------------------------
// transpose + f32->bf16 : src [768, N] (rows offset by rowoff) -> dst [N, 768]
// ---------------------------------------------------------------------------
__global__ __launch_bounds__(256) void transpose_f2b(
    const float* __restrict__ src, unsigned short* __restrict__ dst,
    int N, int rowoff)
{
  __shared__ unsigned short tile[32][33];
  const int nb = blockIdx.x * 32, kb = blockIdx.y * 32;
  const int tx = threadIdx.x & 31, ty = threadIdx.x >> 5;
  #pragma unroll
  for (int i = 0; i < 4; ++i) {
    int k = kb + ty + 8*i, n = nb + tx;
    unsigned short v = 0;
    if (n < N) v = f2b(src[(size_t)(rowoff + k)*N + n]);
    tile[ty + 8*i][tx] = v;
  }
  __syncthreads();
  #pragma unroll
  for (int i = 0; i < 4; ++i) {
    int n = nb + ty + 8*i;
    if (n < N) dst[(size_t)n*768 + kb + tx] = tile[tx][ty + 8*i];
  }
}

// ---------------------------------------------------------------------------
// embedding gather + L2 normalize : emb_all[b*256+t][768]
// ---------------------------------------------------------------------------
__global__ __launch_bounds__(256) void embed_kernel(
    const int* __restrict__ tok, const float* __restrict__ emb,
    float* __restrict__ emb_all)
{
  const int row = blockIdx.x, tid = threadIdx.x;
  const int id = tok[row];
  const float* e = emb + (size_t)id * 768;
  float v0 = e[tid], v1 = e[tid+256], v2 = e[tid+512];
  float ssq = wsum(v0*v0 + v1*v1 + v2*v2);
  __shared__ float red[4];
  if ((tid & 63) == 0) red[tid >> 6] = ssq;
  __syncthreads();
  float inv = 1.0f / fmaxf(sqrtf(red[0]+red[1]+red[2]+red[3]), 1e-12f);
  float* o = emb_all + (size_t)row * 768;
  o[tid] = v0*inv; o[tid+256] = v1*inv; o[tid+512] = v2*inv;
}

// gbias[c] = sum_k c2[k] * Wg[768+k][c]
__global__ void gbias_kernel(const float* __restrict__ c2,
                             const float* __restrict__ Wg,
                             float* __restrict__ gbias)
{
  int c = blockIdx.x * 256 + threadIdx.x;
  if (c >= 768) return;
  float s = 0.f;
  for (int k = 0; k < 768; ++k) s += c2[k] * Wg[(size_t)(768 + k)*768 + c];
  gbias[c] = s;
}

// ---------------------------------------------------------------------------
// GEMM: C[M,N] = A[M,768](f32, bf16-cast) @ B + bias
//   BMODE 0: B = BT bf16 [N,768] (transposed)   BMODE 1: B = f32 [768,N]
// ---------------------------------------------------------------------------
template<int BMODE>
__global__ __launch_bounds__(256) void gemm_kernel(
    const float* __restrict__ A, const void* __restrict__ Bp,
    float* __restrict__ C, const float* __restrict__ bias,
    int M, int N, int q, int r)
{
  const int x = blockIdx.x;
  const int s = blockIdx.y;
  const int mtiles = M >> 6;
  const int cnt_x = q + (x < r ? 1 : 0);
  if (s >= cnt_x * mtiles) return;
  const int off_x = x*q + (x < r ? x : r);
  const int nt = off_x + s / mtiles;
  const int mt = s % mtiles;
  const int m0 = mt << 6, n0 = nt << 6;
  const int w = threadIdx.x >> 6, l = threadIdx.x & 63;
  const int lrow = l & 15, lk8 = (l >> 4) << 3;
  const int arow = m0 + w*16 + lrow;
  f32x4 acc[4] = {f32x4{0,0,0,0}, f32x4{0,0,0,0}, f32x4{0,0,0,0}, f32x4{0,0,0,0}};
  const unsigned short* BT = (const unsigned short*)Bp;
  const float* Bf = (const float*)Bp;

  for (int kk = 0; kk < 768; kk += 32) {
    const float4* ap = (const float4*)(A + (size_t)arow*768 + kk + lk8);
    float4 a0 = ap[0], a1 = ap[1];
    short8 af;
    af[0]=(short)f2b(a0.x); af[1]=(short)f2b(a0.y); af[2]=(short)f2b(a0.z); af[3]=(short)f2b(a0.w);
    af[4]=(short)f2b(a1.x); af[5]=(short)f2b(a1.y); af[6]=(short)f2b(a1.z); af[7]=(short)f2b(a1.w);
    #pragma unroll
    for (int ss = 0; ss < 4; ++ss) {
      const int col = n0 + ss*16 + lrow;
      short8 bf;
      if (BMODE == 0) {
        if (col < N) {
          uint4 raw = *(const uint4*)(BT + (size_t)col*768 + kk + lk8);
          bf = __builtin_bit_cast(short8, raw);
        } else {
          bf = short8{0,0,0,0,0,0,0,0};
        }
      } else {
        #pragma unroll
        for (int j = 0; j < 8; ++j) {
          float v = (col < N) ? Bf[(size_t)(kk + lk8 + j)*N + col] : 0.f;
          bf[j] = (short)f2b(v);
        }
      }
      acc[ss] = __builtin_amdgcn_mfma_f32_16x16x32_bf16(af, bf, acc[ss], 0, 0, 0);
    }
  }
  const int rbase = m0 + w*16 + ((l >> 4) << 2);
  #pragma unroll
  for (int ss = 0; ss < 4; ++ss) {
    const int col = n0 + ss*16 + lrow;
    if (col < N) {
      const float badd = bias ? bias[col] : 0.f;
      #pragma unroll
      for (int rr = 0; rr < 4; ++rr)
        C[(size_t)(rbase + rr)*N + col] = acc[ss][rr] + badd;
    }
  }
}

// ---------------------------------------------------------------------------
// Persistent recurrent kernel: 256 WGs (1/CU), 256 threads.
// WG g owns cols [g*12,+12) of RV0 and [g*3,+3) of V1/W1/W2/W2G/RWt in LDS.
// Transport: write-once step-indexed buffers + 2-level flag tree (header).
//   a1_if : [257 t][4 bb][1024 w] u64, word j = cols 3j..3j+2
//   tg/u/pre_if : [257 t][1024 w] u64, word = G*4+bb -> cols G*3..G*3+2
// ---------------------------------------------------------------------------
__global__ __launch_bounds__(256) void recur_kernel(
    const float* __restrict__ RV0, const float* __restrict__ RWt,
    const float* __restrict__ W1,  const float* __restrict__ W2,
    const float* __restrict__ W2G, const float* __restrict__ V1,
    const float* __restrict__ embV0, const float* __restrict__ embWg,
    const float* __restrict__ gbias, const float* __restrict__ emb_all,
    const float* __restrict__ b1, const float* __restrict__ c1,
    const float* __restrict__ c2, const float* __restrict__ gam,
    const float* __restrict__ bet, float* __restrict__ h_all,
    u64* __restrict__ a1_if, u64* __restrict__ tg_if,
    u64* __restrict__ u_if,  u64* __restrict__ pre_if,
    int* __restrict__ flg)
{
  __shared__ float sRV0[12*768];        // 36864 B
  __shared__ float sV1[3*3072];         // 36864 B
  __shared__ float sW1[3*768];
  __shared__ float sW2[3*768];
  __shared__ float sW2G[3*768];
  __shared__ float sRWt[3*768];         // 4 x 9216 B
  __shared__ float sX[4*768];           // 12288 B
  __shared__ float sX2[4*768];          // 12288 B
  __shared__ unsigned short sA1[4*3072];// 24576 B
  __shared__ float sRed[240];           // 960 B
  __shared__ float sTf[16];             // 64 B   -- total 160768 B

  const int g = blockIdx.x, tid = threadIdx.x;
  const int wv = tid >> 6, lane = tid & 63;
  const bool isAgg = (g < 16);

  // ---- load weight slices into LDS ----
  for (int i = tid; i < 12*768; i += 256) {
    int k = i / 12, c = i - k*12;
    sRV0[c*768 + k] = RV0[(size_t)k*3072 + g*12 + c];
  }
  for (int i = tid; i < 3*3072; i += 256) {
    int k = i / 3, c = i - k*3;
    sV1[c*3072 + k] = V1[(size_t)k*768 + g*3 + c];
  }
  for (int i = tid; i < 3*768; i += 256) {
    int k = i / 3, c = i - k*3;
    const int gc = g*3 + c;
    sW1[c*768 + k]  = W1[(size_t)k*768 + gc];
    sW2[c*768 + k]  = W2[(size_t)k*768 + gc];
    sW2G[c*768 + k] = W2G[(size_t)k*768 + gc];
    sRWt[c*768 + k] = RWt[(size_t)k*768 + gc];
  }
  for (int i = tid; i < 4*768; i += 256) sX2[i] = 0.f;
  __syncthreads();

  for (int t = 0; t <= 256; ++t) {
    // ================= h_{t-1} from fused pre-LN words =================
    if (t == 0) {
      for (int i = tid; i < 4*768; i += 256) sX[i] = 0.f;
    } else {
      // level-1 aggregation of FPRE (producers stored t at step t-1)
      if (isAgg) {
        if (tid < 16)
          while (ldflag(flg + FPRE + g*16 + tid) < t) __builtin_amdgcn_s_sleep(2);
        __syncthreads();
        if (tid == 0) stflag(flg + F2PRE + g, t);
      }
      if (tid < 16)
        while (ldflag(flg + F2PRE + tid) < t) __builtin_amdgcn_s_sleep(4);
      __syncthreads();
      const u64* pm = pre_if + (size_t)(t-1)*1024 + lane*16 + wv;
      u64 w4[4];
      #pragma unroll
      for (int qq = 0; qq < 4; ++qq) w4[qq] = pm[qq*4];   // plain, L2-served
      float pre[12];
      #pragma unroll
      for (int qq = 0; qq < 4; ++qq) {
        pre[qq*3+0] = b2f((unsigned short)(w4[qq]));
        pre[qq*3+1] = b2f((unsigned short)(w4[qq] >> 16));
        pre[qq*3+2] = b2f((unsigned short)(w4[qq] >> 32));
      }
      float s1 = 0.f;
      #pragma unroll
      for (int i = 0; i < 12; ++i) s1 += pre[i];
      s1 = wsum(s1);
      const float mean = s1 * (1.0f/768.0f);
      float s2 = 0.f;
      #pragma unroll
      for (int i = 0; i < 12; ++i) { const float d = pre[i] - mean; s2 += d*d; }
      s2 = wsum(s2);
      const float rstd = 1.0f / sqrtf(s2*(1.0f/768.0f) + 1e-5f);
      const int k0 = lane*12;
      float hv[12];
      #pragma unroll
      for (int i = 0; i < 12; ++i) {
        hv[i] = (pre[i] - mean)*rstd*gam[k0+i] + bet[k0+i];
        sX[wv*768 + k0 + i] = hv[i];
      }
      if (g == 0) {
        float* hp = h_all + (size_t)(wv*256 + t - 1)*768 + k0;
        #pragma unroll
        for (int i = 0; i < 12; ++i) hp[i] = hv[i];
      }
    }
    __syncthreads();
    if (t == 256) break;
    const unsigned tagp = (unsigned)(t + 1);
    const int want = t + 1;

    // ================= P1: a1 slice (12 cols), tf slice (LDS stash) ========
    {
      const int cg = tid >> 6, ks = tid & 63;
      float acc[4][4] = {};
      for (int i = 0; i < 12; ++i) {
        const int k = ks + 64*i;
        const float x0 = sX[k], x1 = sX[768+k], x2v = sX[1536+k], x3 = sX[2304+k];
        #pragma unroll
        for (int j = 0; j < 4; ++j) {
          float w;
          if (cg < 3) w = sRV0[(cg*4 + j)*768 + k];
          else        w = (j < 3) ? sRWt[j*768 + k] : 0.f;
          acc[j][0] += w*x0; acc[j][1] += w*x1; acc[j][2] += w*x2v; acc[j][3] += w*x3;
        }
      }
      #pragma unroll
      for (int j = 0; j < 4; ++j)
        #pragma unroll
        for (int bb = 0; bb < 4; ++bb) {
          const float v = wsum(acc[j][bb]);
          if (lane == 0) sRed[cg*16 + j*4 + bb] = v;
        }
      __syncthreads();
      if (tid < 16) {               // 16 a1 words: bb = tid&3, w = tid>>2
        const int bb = tid & 3, w = tid >> 2;
        float v[3];
        #pragma unroll
        for (int s = 0; s < 3; ++s) {
          const int c = w*3 + s;    // 0..11
          const float raw = sRed[(c >> 2)*16 + (c & 3)*4 + bb];
          v[s] = geluf(embV0[(size_t)(bb*256 + t)*3072 + g*12 + c] + 0.4f*raw);
        }
        st64(a1_if + (size_t)t*4096 + bb*1024 + g*4 + w, pk3t(v[0], v[1], v[2], tagp));
      } else if (tid < 20) {        // stash tf slice for P4's fused pre
        const int bb = tid - 16;
        sTf[bb]     = sRed[48 + bb];
        sTf[4 + bb] = sRed[52 + bb];
        sTf[8 + bb] = sRed[56 + bb];
      }
      vm0();
      __syncthreads();
      if (tid == 0) stflag(flg + FA1 + g, want);
    }

    // ================= P2: target slice =================
    {
      if (isAgg) {
        if (tid < 16)
          while (ldflag(flg + FA1 + g*16 + tid) < want) __builtin_amdgcn_s_sleep(2);
        __syncthreads();
        if (tid == 0) stflag(flg + F2A1 + g, want);
      }
      if (tid < 16)
        while (ldflag(flg + F2A1 + tid) < want) __builtin_amdgcn_s_sleep(4);
      __syncthreads();
      const u64* basep = a1_if + (size_t)t*4096;
      u64 x[16];
      #pragma unroll
      for (int i = 0; i < 16; ++i) x[i] = basep[i*256 + tid];  // plain, coalesced
      #pragma unroll
      for (int i = 0; i < 16; ++i) {
        const int widx = i*256 + tid;       // [0,4096)
        const int bb = widx >> 10, j = widx & 1023;
        sA1[bb*3072 + 3*j + 0] = (unsigned short)(x[i]);
        sA1[bb*3072 + 3*j + 1] = (unsigned short)(x[i] >> 16);
        sA1[bb*3072 + 3*j + 2] = (unsigned short)(x[i] >> 32);
      }
      __syncthreads();
      const int ks = lane, isub = wv;
      float acc[3][4] = {};
      for (int ip = 0; ip < 12; ++ip) {
        const int k = ks + 64*(isub + 4*ip);
        float xv[4];
        #pragma unroll
        for (int bb = 0; bb < 4; ++bb) xv[bb] = b2f(sA1[bb*3072 + k]);
        #pragma unroll
        for (int c = 0; c < 3; ++c) {
          const float w = sV1[c*3072 + k];
          acc[c][0] += w*xv[0]; acc[c][1] += w*xv[1]; acc[c][2] += w*xv[2]; acc[c][3] += w*xv[3];
        }
      }
      #pragma unroll
      for (int c = 0; c < 3; ++c)
        #pragma unroll
        for (int bb = 0; bb < 4; ++bb) {
          const float v = wsum(acc[c][bb]);
          if (lane == 0) sRed[isub*12 + c*4 + bb] = v;
        }
      __syncthreads();
      if (tid < 4) {
        const int bb = tid;
        float v[3];
        #pragma unroll
        for (int c = 0; c < 3; ++c) {
          float s = sRed[c*4+bb] + sRed[12 + c*4+bb] + sRed[24 + c*4+bb] + sRed[36 + c*4+bb];
          v[c] = geluf(s + b1[g*3 + c]);
        }
        st64(tg_if + (size_t)t*1024 + g*4 + bb, pk3t(v[0], v[1], v[2], tagp));
      }
      vm0();
      __syncthreads();
      if (tid == 0) stflag(flg + FTG + g, want);
    }

    // ================= P3: x2 EMA, cb, u slice =================
    {
      if (isAgg) {
        if (tid < 16)
          while (ldflag(flg + FTG + g*16 + tid) < want) __builtin_amdgcn_s_sleep(2);
        __syncthreads();
        if (tid == 0) stflag(flg + F2TG + g, want);
      }
      if (tid < 16)
        while (ldflag(flg + F2TG + tid) < want) __builtin_amdgcn_s_sleep(4);
      __syncthreads();
      const u64* pm = tg_if + (size_t)t*1024 + lane*16 + wv;
      u64 w4[4];
      #pragma unroll
      for (int qq = 0; qq < 4; ++qq) w4[qq] = pm[qq*4];
      float tv[12];
      #pragma unroll
      for (int qq = 0; qq < 4; ++qq) {
        tv[qq*3+0] = b2f((unsigned short)(w4[qq]));
        tv[qq*3+1] = b2f((unsigned short)(w4[qq] >> 16));
        tv[qq*3+2] = b2f((unsigned short)(w4[qq] >> 32));
      }
      const int xb = wv*768 + lane*12;
      float xv2[12];
      float ssqT = 0.f, ssqX = 0.f;
      #pragma unroll
      for (int i = 0; i < 12; ++i) {
        float xx = sX2[xb + i];
        const float tt = tv[i];
        #pragma unroll
        for (int rr = 0; rr < 10; ++rr) xx = 0.5f*xx + 0.5f*tt;
        sX2[xb + i] = xx; xv2[i] = xx;
        ssqT += tt*tt; ssqX += xx*xx;
      }
      ssqT = wsum(ssqT); ssqX = wsum(ssqX);
      const float invT = 1.0f / fmaxf(sqrtf(ssqT), 1e-12f);
      const float invX = 1.0f / fmaxf(sqrtf(ssqX), 1e-12f);
      #pragma unroll
      for (int i = 0; i < 12; ++i) sX[xb + i] = 0.5f*(tv[i]*invT + xv2[i]*invX);
      __syncthreads();
      const int ks = lane, isub = wv;
      float acc[3][4] = {};
      #pragma unroll
      for (int ip = 0; ip < 3; ++ip) {
        const int k = ks + 64*(isub + 4*ip);
        float xv[4];
        #pragma unroll
        for (int bb = 0; bb < 4; ++bb) xv[bb] = sX[bb*768 + k];
        #pragma unroll
        for (int c = 0; c < 3; ++c) {
          const float w = sW1[c*768 + k];
          acc[c][0] += w*xv[0]; acc[c][1] += w*xv[1]; acc[c][2] += w*xv[2]; acc[c][3] += w*xv[3];
        }
      }
      #pragma unroll
      for (int c = 0; c < 3; ++c)
        #pragma unroll
        for (int bb = 0; bb < 4; ++bb) {
          const float v = wsum(acc[c][bb]);
          if (lane == 0) sRed[isub*12 + c*4 + bb] = v;
        }
      __syncthreads();
      if (tid < 4) {
        const int bb = tid;
        float v[3];
        #pragma unroll
        for (int c = 0; c < 3; ++c) {
          float s = sRed[c*4+bb] + sRed[12 + c*4+bb] + sRed[24 + c*4+bb] + sRed[36 + c*4+bb];
          v[c] = geluf(s + c1[g*3 + c]);
        }
        st64(u_if + (size_t)t*1024 + g*4 + bb, pk3t(v[0], v[1], v[2], tagp));
      }
      vm0();
      __syncthreads();
      if (tid == 0) stflag(flg + FU + g, want);
    }

    // ================= P4: cf/gv -> fused pre-LN slice =================
    {
      if (isAgg) {
        if (tid < 16)
          while (ldflag(flg + FU + g*16 + tid) < want) __builtin_amdgcn_s_sleep(2);
        __syncthreads();
        if (tid == 0) stflag(flg + F2U + g, want);
      }
      if (tid < 16)
        while (ldflag(flg + F2U + tid) < want) __builtin_amdgcn_s_sleep(4);
      __syncthreads();
      const u64* pm = u_if + (size_t)t*1024 + lane*16 + wv;
      u64 w4[4];
      #pragma unroll
      for (int qq = 0; qq < 4; ++qq) w4[qq] = pm[qq*4];
      const int xb = wv*768 + lane*12;
      #pragma unroll
      for (int qq = 0; qq < 4; ++qq) {
        sX[xb + qq*3 + 0] = b2f((unsigned short)(w4[qq]));
        sX[xb + qq*3 + 1] = b2f((unsigned short)(w4[qq] >> 16));
        sX[xb + qq*3 + 2] = b2f((unsigned short)(w4[qq] >> 32));
      }
      __syncthreads();
      const int ks = lane, isub = wv;
      float acc[6][4] = {};
      #pragma unroll
      for (int ip = 0; ip < 3; ++ip) {
        const int k = ks + 64*(isub + 4*ip);
        float xv[4];
        #pragma unroll
        for (int bb = 0; bb < 4; ++bb) xv[bb] = sX[bb*768 + k];
        #pragma unroll
        for (int c = 0; c < 6; ++c) {
          const float w = (c < 3) ? sW2[c*768 + k] : sW2G[(c-3)*768 + k];
          acc[c][0] += w*xv[0]; acc[c][1] += w*xv[1]; acc[c][2] += w*xv[2]; acc[c][3] += w*xv[3];
        }
      }
      #pragma unroll
      for (int c = 0; c < 6; ++c)
        #pragma unroll
        for (int bb = 0; bb < 4; ++bb) {
          const float v = wsum(acc[c][bb]);
          if (lane == 0) sRed[isub*24 + c*4 + bb] = v;
        }
      __syncthreads();
      if (tid < 4) {
        const int bb = tid;
        float pre3[3];
        #pragma unroll
        for (int c = 0; c < 3; ++c) {
          const int col = g*3 + c;
          float sc = sRed[c*4+bb] + sRed[24 + c*4+bb] + sRed[48 + c*4+bb] + sRed[72 + c*4+bb];
          const float cf = sc + c2[col];
          const int cc = c + 3;
          float sg = sRed[cc*4+bb] + sRed[24 + cc*4+bb] + sRed[48 + cc*4+bb] + sRed[72 + cc*4+bb];
          const float gv = sg + embWg[(size_t)(bb*256 + t)*768 + col] + gbias[col];
          const float gg = 1.0f / (1.0f + expf(-gv));
          const float em = emb_all[(size_t)(bb*256 + t)*768 + col];
          pre3[c] = gg*(cf + 0.4f*sTf[c*4 + bb]) + (1.0f - gg)*em;
        }
        st64(pre_if + (size_t)t*1024 + g*4 + bb, pk3t(pre3[0], pre3[1], pre3[2], tagp));
      }
      vm0();
      __syncthreads();
      if (tid == 0) stflag(flg + FPRE + g, want);
    }
  }
}

// ---------------------------------------------------------------------------
// host
// ---------------------------------------------------------------------------
static void launch_gemm(const float* A, const void* B, float* C, const float* bias,
                        int M, int N, int bmode, hipStream_t st)
{
  const int ntiles = (N + 63) / 64;
  const int q = ntiles / 8, r = ntiles % 8;
  const int mtiles = M / 64;
  const int smax = (q + (r ? 1 : 0)) * mtiles;
  dim3 grid(8, smax);
  if (bmode == 0) gemm_kernel<0><<<grid, 256, 0, st>>>(A, B, C, bias, M, N, q, r);
  else            gemm_kernel<1><<<grid, 256, 0, st>>>(A, B, C, bias, M, N, q, r);
}

extern "C" void kernel_launch(void* const* d_in, const int* in_sizes, int n_in,
                              void* d_out, int out_size, void* d_ws, size_t ws_size,
                              hipStream_t stream)
{
  const int*   tok   = (const int*)d_in[0];
  const float* emb   = (const float*)d_in[1];
  const float* V0    = (const float*)d_in[2];
  const float* b0    = (const float*)d_in[3];
  const float* V1    = (const float*)d_in[4];
  const float* b1    = (const float*)d_in[5];
  const float* W1    = (const float*)d_in[6];
  const float* c1    = (const float*)d_in[7];
  const float* W2    = (const float*)d_in[8];
  const float* c2    = (const float*)d_in[9];
  const float* Wg    = (const float*)d_in[10];
  const float* bg    = (const float*)d_in[11];
  const float* Wt    = (const float*)d_in[12];
  const float* gamma = (const float*)d_in[13];
  const float* beta  = (const float*)d_in[14];
  const float* Wl    = (const float*)d_in[15];
  const float* Rw    = (const float*)d_in[16];

  float* outf = (float*)d_out;
  // scratch carved from d_out (all consumed before the final GEMM overwrites)
  float* emb_all = outf + 0;                    //  786432
  float* RV0     = outf + 786432;               // 2359296
  float* RWt     = outf + 3145728;              //  589824
  float* W2G     = outf + 3735552;              //  589824
  float* embV0   = outf + 4325376;              // 3145728
  float* embWg   = outf + 7471104;              //  786432
  float* gbias   = outf + 8257536;              //    1024
  unsigned short* V0T  = (unsigned short*)(outf + 8258560);   // 2359296 el
  unsigned short* WtT  = (unsigned short*)(outf + 9438208);   //  589824 el
  unsigned short* WgTT = (unsigned short*)(outf + 9733120);   //  589824 el
  unsigned short* WgBT = (unsigned short*)(outf + 10028032);  //  589824 el
  u64* a1_if  = (u64*)(outf + 10322944);  // 257*4096 u64 -> 2105344 f
  u64* tg_if  = (u64*)(outf + 12428288);  // 257*1024 u64 ->  526336 f
  u64* u_if   = (u64*)(outf + 12954624);
  u64* pre_if = (u64*)(outf + 13480960);
  int* flg    = (int*)(outf + 14007296);  // 2048 ints (flag0 1024 + flag1 tree)
                                          // end 14009344 < 51463168

  float* h_all = (float*)d_ws;                                // 786432 f32
  unsigned short* WlT = (unsigned short*)((char*)d_ws + 786432*4);
  const bool bigws = ws_size >= (size_t)(786432*4) + (size_t)38597376*2 + 256;

  hipMemsetAsync(flg, 0, 2048 * sizeof(int), stream);

  // transposed bf16 copies of GEMM B operands
  transpose_f2b<<<dim3(96, 24),   256, 0, stream>>>(V0, V0T, 3072, 0);
  transpose_f2b<<<dim3(24, 24),   256, 0, stream>>>(Wt, WtT, 768, 0);
  transpose_f2b<<<dim3(24, 24),   256, 0, stream>>>(Wg, WgTT, 768, 0);
  transpose_f2b<<<dim3(24, 24),   256, 0, stream>>>(Wg, WgBT, 768, 768);
  if (bigws)
    transpose_f2b<<<dim3(1572, 24), 256, 0, stream>>>(Wl, WlT, 50257, 0);

  embed_kernel<<<1024, 256, 0, stream>>>(tok, emb, emb_all);
  gbias_kernel<<<3, 256, 0, stream>>>(c2, Wg, gbias);

  // fused-weight + per-token precompute GEMMs (bf16 MFMA, fp32 out)
  launch_gemm(Rw,      V0T,  RV0,   nullptr, 768,  3072, 0, stream);
  launch_gemm(Rw,      WtT,  RWt,   nullptr, 768,  768,  0, stream);
  launch_gemm(W2,      WgBT, W2G,   nullptr, 768,  768,  0, stream);
  launch_gemm(emb_all, V0T,  embV0, b0,      1024, 3072, 0, stream);
  launch_gemm(emb_all, WgTT, embWg, bg,      1024, 768,  0, stream);

  // the sequential part
  recur_kernel<<<256, 256, 0, stream>>>(
      RV0, RWt, W1, W2, W2G, V1, embV0, embWg, gbias, emb_all,
      b1, c1, c2, gamma, beta, h_all,
      a1_if, tg_if, u_if, pre_if, flg);

  // deferred lm_head: logits[b*256+t][v] = h_all @ Wl
  if (bigws) launch_gemm(h_all, WlT, outf, nullptr, 1024, 50257, 0, stream);
  else       launch_gemm(h_all, Wl,  outf, nullptr, 1024, 50257, 1, stream);
}

// Round 9
// 8768.444 us; speedup vs baseline: 4.3786x; 1.1854x over previous
//
#include <hip/hip_runtime.h>

// ============================================================================
// AgnisV5: sequential recurrence (4-phase persistent kernel, weights in LDS)
//          + deferred batched lm_head GEMM (bf16 MFMA).
//
// Round-8 change: PER-LINE POLL PRESSURE FIX (H4). Evidence R2/R3/R6/R7: the
// sync-completing store always lands on a cache line receiving 4k-16k poll
// requests/us while an IF$ bank services ~2.4k/us -> the store queues behind
// a multi-us poll backlog; cost ~9us/phase, protocol-invariant. Now every
// flag lives on its OWN 64B line:
//   flag0[ph][g]  : 4x256 lines, each polled by EXACTLY ONE aggregator thread
//   flag1[ph][a]  : 4x16 lines, each polled by 1 thread/WG (256 pollers,
//                   s_sleep(8)-throttled -> ~500 req/us/line, under capacity)
// Latency shaving: step-invariant loads (gam/bet/b1/c1/c2/gbias) hoisted out
// of the loop; step-t token slices (embV0/embWg/emb) prefetched into LDS by
// waves 1-2 WHILE wave 0 polls; h-phase emb row loads issued before the poll.
// Payload transport unchanged from R6/R7 (write-once step-indexed buffers,
// plain L2-fanout loads). All primitives proven in R2/R3/R6/R7.
// ============================================================================

typedef __attribute__((ext_vector_type(8))) short short8;
typedef __attribute__((ext_vector_type(4))) float f32x4;
typedef unsigned long long u64;

__device__ __forceinline__ unsigned short f2b(float f){
  unsigned int u = __builtin_bit_cast(unsigned int, f);
  u += 0x7fffu + ((u >> 16) & 1u);
  return (unsigned short)(u >> 16);
}
__device__ __forceinline__ float b2f(unsigned short v){
  return __builtin_bit_cast(float, ((unsigned int)v) << 16);
}
__device__ __forceinline__ float geluf(float x){
  return 0.5f * x * (1.0f + erff(x * 0.70710678118654752440f));
}
__device__ __forceinline__ float wsum(float v){
  #pragma unroll
  for (int o = 32; o; o >>= 1) v += __shfl_xor(v, o, 64);
  return v;
}
__device__ __forceinline__ u64 pk3t(float a, float b, float c, unsigned tag){
  return (u64)f2b(a) | ((u64)f2b(b) << 16) | ((u64)f2b(c) << 32) | ((u64)(tag & 0xffffu) << 48);
}
// sc1 (IF$-coherent) accessors — the only cross-XCD-visible ops we use
__device__ __forceinline__ void st64(u64* p, u64 v){
  __hip_atomic_store(p, v, __ATOMIC_RELAXED, __HIP_MEMORY_SCOPE_AGENT);
}
__device__ __forceinline__ void stflag(int* p, int v){
  __hip_atomic_store(p, v, __ATOMIC_RELAXED, __HIP_MEMORY_SCOPE_AGENT);
}
__device__ __forceinline__ int ldflag(const int* p){
  return __hip_atomic_load(p, __ATOMIC_RELAXED, __HIP_MEMORY_SCOPE_AGENT);
}
__device__ __forceinline__ void vm0(){ asm volatile("s_waitcnt vmcnt(0)" ::: "memory"); }

// flag layout: every flag on its own 64B (16-int) line.
//   flag0: idx (ph,g)  -> (ph*256+g)*16          [ph 0..3, g 0..255]
//   flag1: idx (ph,a)  -> 16384 + (ph*16+a)*16   [a 0..15]
#define F0(ph,g) (((ph)*256 + (g))*16)
#define F1(ph,a) (16384 + ((ph)*16 + (a))*16)
// phases: 0=A1, 1=TG, 2=U, 3=PRE

// ---------------------------------------------------------------------------
// transpose + f32->bf16 : src [768, N] (rows offset by rowoff) -> dst [N, 768]
// ---------------------------------------------------------------------------
__global__ __launch_bounds__(256) void transpose_f2b(
    const float* __restrict__ src, unsigned short* __restrict__ dst,
    int N, int rowoff)
{
  __shared__ unsigned short tile[32][33];
  const int nb = blockIdx.x * 32, kb = blockIdx.y * 32;
  const int tx = threadIdx.x & 31, ty = threadIdx.x >> 5;
  #pragma unroll
  for (int i = 0; i < 4; ++i) {
    int k = kb + ty + 8*i, n = nb + tx;
    unsigned short v = 0;
    if (n < N) v = f2b(src[(size_t)(rowoff + k)*N + n]);
    tile[ty + 8*i][tx] = v;
  }
  __syncthreads();
  #pragma unroll
  for (int i = 0; i < 4; ++i) {
    int n = nb + ty + 8*i;
    if (n < N) dst[(size_t)n*768 + kb + tx] = tile[tx][ty + 8*i];
  }
}

// ---------------------------------------------------------------------------
// embedding gather + L2 normalize : emb_all[b*256+t][768]
// ---------------------------------------------------------------------------
__global__ __launch_bounds__(256) void embed_kernel(
    const int* __restrict__ tok, const float* __restrict__ emb,
    float* __restrict__ emb_all)
{
  const int row = blockIdx.x, tid = threadIdx.x;
  const int id = tok[row];
  const float* e = emb + (size_t)id * 768;
  float v0 = e[tid], v1 = e[tid+256], v2 = e[tid+512];
  float ssq = wsum(v0*v0 + v1*v1 + v2*v2);
  __shared__ float red[4];
  if ((tid & 63) == 0) red[tid >> 6] = ssq;
  __syncthreads();
  float inv = 1.0f / fmaxf(sqrtf(red[0]+red[1]+red[2]+red[3]), 1e-12f);
  float* o = emb_all + (size_t)row * 768;
  o[tid] = v0*inv; o[tid+256] = v1*inv; o[tid+512] = v2*inv;
}

// gbias[c] = sum_k c2[k] * Wg[768+k][c]
__global__ void gbias_kernel(const float* __restrict__ c2,
                             const float* __restrict__ Wg,
                             float* __restrict__ gbias)
{
  int c = blockIdx.x * 256 + threadIdx.x;
  if (c >= 768) return;
  float s = 0.f;
  for (int k = 0; k < 768; ++k) s += c2[k] * Wg[(size_t)(768 + k)*768 + c];
  gbias[c] = s;
}

// ---------------------------------------------------------------------------
// GEMM: C[M,N] = A[M,768](f32, bf16-cast) @ B + bias
//   BMODE 0: B = BT bf16 [N,768] (transposed)   BMODE 1: B = f32 [768,N]
// ---------------------------------------------------------------------------
template<int BMODE>
__global__ __launch_bounds__(256) void gemm_kernel(
    const float* __restrict__ A, const void* __restrict__ Bp,
    float* __restrict__ C, const float* __restrict__ bias,
    int M, int N, int q, int r)
{
  const int x = blockIdx.x;
  const int s = blockIdx.y;
  const int mtiles = M >> 6;
  const int cnt_x = q + (x < r ? 1 : 0);
  if (s >= cnt_x * mtiles) return;
  const int off_x = x*q + (x < r ? x : r);
  const int nt = off_x + s / mtiles;
  const int mt = s % mtiles;
  const int m0 = mt << 6, n0 = nt << 6;
  const int w = threadIdx.x >> 6, l = threadIdx.x & 63;
  const int lrow = l & 15, lk8 = (l >> 4) << 3;
  const int arow = m0 + w*16 + lrow;
  f32x4 acc[4] = {f32x4{0,0,0,0}, f32x4{0,0,0,0}, f32x4{0,0,0,0}, f32x4{0,0,0,0}};
  const unsigned short* BT = (const unsigned short*)Bp;
  const float* Bf = (const float*)Bp;

  for (int kk = 0; kk < 768; kk += 32) {
    const float4* ap = (const float4*)(A + (size_t)arow*768 + kk + lk8);
    float4 a0 = ap[0], a1 = ap[1];
    short8 af;
    af[0]=(short)f2b(a0.x); af[1]=(short)f2b(a0.y); af[2]=(short)f2b(a0.z); af[3]=(short)f2b(a0.w);
    af[4]=(short)f2b(a1.x); af[5]=(short)f2b(a1.y); af[6]=(short)f2b(a1.z); af[7]=(short)f2b(a1.w);
    #pragma unroll
    for (int ss = 0; ss < 4; ++ss) {
      const int col = n0 + ss*16 + lrow;
      short8 bf;
      if (BMODE == 0) {
        if (col < N) {
          uint4 raw = *(const uint4*)(BT + (size_t)col*768 + kk + lk8);
          bf = __builtin_bit_cast(short8, raw);
        } else {
          bf = short8{0,0,0,0,0,0,0,0};
        }
      } else {
        #pragma unroll
        for (int j = 0; j < 8; ++j) {
          float v = (col < N) ? Bf[(size_t)(kk + lk8 + j)*N + col] : 0.f;
          bf[j] = (short)f2b(v);
        }
      }
      acc[ss] = __builtin_amdgcn_mfma_f32_16x16x32_bf16(af, bf, acc[ss], 0, 0, 0);
    }
  }
  const int rbase = m0 + w*16 + ((l >> 4) << 2);
  #pragma unroll
  for (int ss = 0; ss < 4; ++ss) {
    const int col = n0 + ss*16 + lrow;
    if (col < N) {
      const float badd = bias ? bias[col] : 0.f;
      #pragma unroll
      for (int rr = 0; rr < 4; ++rr)
        C[(size_t)(rbase + rr)*N + col] = acc[ss][rr] + badd;
    }
  }
}

// ---------------------------------------------------------------------------
// Persistent recurrent kernel: 256 WGs (1/CU), 256 threads.
// WG g owns cols [g*12,+12) of RV0 and [g*3,+3) of V1/W1/W2/W2G/RWt in LDS.
//   a1_if : [257 t][4 bb][1024 w] u64, word j = cols 3j..3j+2
//   tg/u/pre_if : [257 t][1024 w] u64, word = G*4+bb -> cols G*3..G*3+2
// ---------------------------------------------------------------------------
__global__ __launch_bounds__(256) void recur_kernel(
    const float* __restrict__ RV0, const float* __restrict__ RWt,
    const float* __restrict__ W1,  const float* __restrict__ W2,
    const float* __restrict__ W2G, const float* __restrict__ V1,
    const float* __restrict__ embV0, const float* __restrict__ embWg,
    const float* __restrict__ gbias, const float* __restrict__ emb_all,
    const float* __restrict__ b1, const float* __restrict__ c1,
    const float* __restrict__ c2, const float* __restrict__ gam,
    const float* __restrict__ bet, float* __restrict__ h_all,
    u64* __restrict__ a1_if, u64* __restrict__ tg_if,
    u64* __restrict__ u_if,  u64* __restrict__ pre_if,
    int* __restrict__ flg)
{
  __shared__ float sRV0[12*768];        // 36864 B
  __shared__ float sV1[3*3072];         // 36864 B
  __shared__ float sW1[3*768];
  __shared__ float sW2[3*768];
  __shared__ float sW2G[3*768];
  __shared__ float sRWt[3*768];         // 4 x 9216 B
  __shared__ float sX[4*768];           // 12288 B
  __shared__ float sX2[4*768];          // 12288 B
  __shared__ unsigned short sA1[4*3072];// 24576 B
  __shared__ float sRed[240];           // 960 B
  __shared__ float sTf[16];             // 64 B
  __shared__ float sCst[12];            // b1/c1/c2/gbias slices (step-invariant)
  __shared__ float sEV0[48];            // embV0 step-t slice (prefetched)
  __shared__ float sEWg[12];            // embWg step-t slice
  __shared__ float sEmb[12];            // emb_all step-t slice (P4)

  const int g = blockIdx.x, tid = threadIdx.x;
  const int wv = tid >> 6, lane = tid & 63;
  const bool isAgg = (g < 16);

  // ---- load weight slices into LDS ----
  for (int i = tid; i < 12*768; i += 256) {
    int k = i / 12, c = i - k*12;
    sRV0[c*768 + k] = RV0[(size_t)k*3072 + g*12 + c];
  }
  for (int i = tid; i < 3*3072; i += 256) {
    int k = i / 3, c = i - k*3;
    sV1[c*3072 + k] = V1[(size_t)k*768 + g*3 + c];
  }
  for (int i = tid; i < 3*768; i += 256) {
    int k = i / 3, c = i - k*3;
    const int gc = g*3 + c;
    sW1[c*768 + k]  = W1[(size_t)k*768 + gc];
    sW2[c*768 + k]  = W2[(size_t)k*768 + gc];
    sW2G[c*768 + k] = W2G[(size_t)k*768 + gc];
    sRWt[c*768 + k] = RWt[(size_t)k*768 + gc];
  }
  for (int i = tid; i < 4*768; i += 256) sX2[i] = 0.f;
  // step-invariant per-WG constants
  if (tid < 3)       sCst[tid]     = b1[g*3 + tid];
  else if (tid < 6)  sCst[tid]     = c1[g*3 + tid - 3];
  else if (tid < 9)  sCst[tid]     = c2[g*3 + tid - 6];
  else if (tid < 12) sCst[tid]     = gbias[g*3 + tid - 9];
  // step-invariant LN params (per-thread registers)
  const int k0 = lane*12;
  float gamv[12], betv[12];
  #pragma unroll
  for (int i = 0; i < 12; ++i) { gamv[i] = gam[k0+i]; betv[i] = bet[k0+i]; }
  __syncthreads();

  for (int t = 0; t <= 256; ++t) {
    // ---- prefetch step-t token slices (waves 1-2; overlaps h-phase poll) ---
    if (t < 256) {
      if (tid >= 64 && tid < 112) {
        const int j = tid - 64, bb = j & 3, c = j >> 2;   // c 0..11
        sEV0[c*4 + bb] = embV0[(size_t)(bb*256 + t)*3072 + g*12 + c];
      } else if (tid >= 128 && tid < 140) {
        const int j = tid - 128, bb = j & 3, c = j >> 2;  // c 0..2
        sEWg[c*4 + bb] = embWg[(size_t)(bb*256 + t)*768 + g*3 + c];
      } else if (tid >= 140 && tid < 152) {
        const int j = tid - 140, bb = j & 3, c = j >> 2;
        sEmb[c*4 + bb] = emb_all[(size_t)(bb*256 + t)*768 + g*3 + c];
      }
    }

    // ================= h_{t-1} from fused pre-LN words =================
    if (t == 0) {
      for (int i = tid; i < 4*768; i += 256) sX[i] = 0.f;
    } else {
      // issue emb row loads BEFORE the poll (in flight during wait)
      float4 e0, e1, e2;
      {
        const float4* q4 = (const float4*)(emb_all + (size_t)(wv*256 + t - 1)*768 + lane*12);
        e0 = q4[0]; e1 = q4[1]; e2 = q4[2];
      }
      (void)e0; (void)e1; (void)e2;
      // tree wait on FPRE (producers stored t at end of step t-1)
      if (isAgg) {
        if (tid < 16)
          while (ldflag(flg + F0(3, g*16 + tid)) < t) __builtin_amdgcn_s_sleep(2);
        __syncthreads();
        if (tid == 0) stflag(flg + F1(3, g), t);
      }
      if (tid < 16)
        while (ldflag(flg + F1(3, tid)) < t) __builtin_amdgcn_s_sleep(8);
      __syncthreads();
      const u64* pm = pre_if + (size_t)(t-1)*1024 + lane*16 + wv;
      u64 w4[4];
      #pragma unroll
      for (int qq = 0; qq < 4; ++qq) w4[qq] = pm[qq*4];   // plain, L2-served
      float pre[12];
      #pragma unroll
      for (int qq = 0; qq < 4; ++qq) {
        pre[qq*3+0] = b2f((unsigned short)(w4[qq]));
        pre[qq*3+1] = b2f((unsigned short)(w4[qq] >> 16));
        pre[qq*3+2] = b2f((unsigned short)(w4[qq] >> 32));
      }
      float s1 = 0.f;
      #pragma unroll
      for (int i = 0; i < 12; ++i) s1 += pre[i];
      s1 = wsum(s1);
      const float mean = s1 * (1.0f/768.0f);
      float s2 = 0.f;
      #pragma unroll
      for (int i = 0; i < 12; ++i) { const float d = pre[i] - mean; s2 += d*d; }
      s2 = wsum(s2);
      const float rstd = 1.0f / sqrtf(s2*(1.0f/768.0f) + 1e-5f);
      float hv[12];
      #pragma unroll
      for (int i = 0; i < 12; ++i) {
        hv[i] = (pre[i] - mean)*rstd*gamv[i] + betv[i];
        sX[wv*768 + k0 + i] = hv[i];
      }
      if (g == 0) {
        float* hp = h_all + (size_t)(wv*256 + t - 1)*768 + k0;
        #pragma unroll
        for (int i = 0; i < 12; ++i) hp[i] = hv[i];
      }
    }
    __syncthreads();
    if (t == 256) break;
    const unsigned tagp = (unsigned)(t + 1);
    const int want = t + 1;

    // ================= P1: a1 slice (12 cols), tf slice (LDS stash) ========
    {
      const int cg = tid >> 6, ks = tid & 63;
      float acc[4][4] = {};
      for (int i = 0; i < 12; ++i) {
        const int k = ks + 64*i;
        const float x0 = sX[k], x1 = sX[768+k], x2v = sX[1536+k], x3 = sX[2304+k];
        #pragma unroll
        for (int j = 0; j < 4; ++j) {
          float w;
          if (cg < 3) w = sRV0[(cg*4 + j)*768 + k];
          else        w = (j < 3) ? sRWt[j*768 + k] : 0.f;
          acc[j][0] += w*x0; acc[j][1] += w*x1; acc[j][2] += w*x2v; acc[j][3] += w*x3;
        }
      }
      #pragma unroll
      for (int j = 0; j < 4; ++j)
        #pragma unroll
        for (int bb = 0; bb < 4; ++bb) {
          const float v = wsum(acc[j][bb]);
          if (lane == 0) sRed[cg*16 + j*4 + bb] = v;
        }
      __syncthreads();
      if (tid < 16) {               // 16 a1 words: bb = tid&3, w = tid>>2
        const int bb = tid & 3, w = tid >> 2;
        float v[3];
        #pragma unroll
        for (int s = 0; s < 3; ++s) {
          const int c = w*3 + s;    // 0..11
          const float raw = sRed[(c >> 2)*16 + (c & 3)*4 + bb];
          v[s] = geluf(sEV0[c*4 + bb] + 0.4f*raw);
        }
        st64(a1_if + (size_t)t*4096 + bb*1024 + g*4 + w, pk3t(v[0], v[1], v[2], tagp));
      } else if (tid < 20) {        // stash tf slice for P4's fused pre
        const int bb = tid - 16;
        sTf[bb]     = sRed[48 + bb];
        sTf[4 + bb] = sRed[52 + bb];
        sTf[8 + bb] = sRed[56 + bb];
      }
      vm0();
      __syncthreads();
      if (tid == 0) stflag(flg + F0(0, g), want);
    }

    // ================= P2: target slice =================
    {
      if (isAgg) {
        if (tid < 16)
          while (ldflag(flg + F0(0, g*16 + tid)) < want) __builtin_amdgcn_s_sleep(2);
        __syncthreads();
        if (tid == 0) stflag(flg + F1(0, g), want);
      }
      if (tid < 16)
        while (ldflag(flg + F1(0, tid)) < want) __builtin_amdgcn_s_sleep(8);
      __syncthreads();
      const u64* basep = a1_if + (size_t)t*4096;
      u64 x[16];
      #pragma unroll
      for (int i = 0; i < 16; ++i) x[i] = basep[i*256 + tid];  // plain, coalesced
      #pragma unroll
      for (int i = 0; i < 16; ++i) {
        const int widx = i*256 + tid;       // [0,4096)
        const int bb = widx >> 10, j = widx & 1023;
        sA1[bb*3072 + 3*j + 0] = (unsigned short)(x[i]);
        sA1[bb*3072 + 3*j + 1] = (unsigned short)(x[i] >> 16);
        sA1[bb*3072 + 3*j + 2] = (unsigned short)(x[i] >> 32);
      }
      __syncthreads();
      const int ks = lane, isub = wv;
      float acc[3][4] = {};
      for (int ip = 0; ip < 12; ++ip) {
        const int k = ks + 64*(isub + 4*ip);
        float xv[4];
        #pragma unroll
        for (int bb = 0; bb < 4; ++bb) xv[bb] = b2f(sA1[bb*3072 + k]);
        #pragma unroll
        for (int c = 0; c < 3; ++c) {
          const float w = sV1[c*3072 + k];
          acc[c][0] += w*xv[0]; acc[c][1] += w*xv[1]; acc[c][2] += w*xv[2]; acc[c][3] += w*xv[3];
        }
      }
      #pragma unroll
      for (int c = 0; c < 3; ++c)
        #pragma unroll
        for (int bb = 0; bb < 4; ++bb) {
          const float v = wsum(acc[c][bb]);
          if (lane == 0) sRed[isub*12 + c*4 + bb] = v;
        }
      __syncthreads();
      if (tid < 4) {
        const int bb = tid;
        float v[3];
        #pragma unroll
        for (int c = 0; c < 3; ++c) {
          float s = sRed[c*4+bb] + sRed[12 + c*4+bb] + sRed[24 + c*4+bb] + sRed[36 + c*4+bb];
          v[c] = geluf(s + sCst[c]);
        }
        st64(tg_if + (size_t)t*1024 + g*4 + bb, pk3t(v[0], v[1], v[2], tagp));
      }
      vm0();
      __syncthreads();
      if (tid == 0) stflag(flg + F0(1, g), want);
    }

    // ================= P3: x2 EMA, cb, u slice =================
    {
      if (isAgg) {
        if (tid < 16)
          while (ldflag(flg + F0(1, g*16 + tid)) < want) __builtin_amdgcn_s_sleep(2);
        __syncthreads();
        if (tid == 0) stflag(flg + F1(1, g), want);
      }
      if (tid < 16)
        while (ldflag(flg + F1(1, tid)) < want) __builtin_amdgcn_s_sleep(8);
      __syncthreads();
      const u64* pm = tg_if + (size_t)t*1024 + lane*16 + wv;
      u64 w4[4];
      #pragma unroll
      for (int qq = 0; qq < 4; ++qq) w4[qq] = pm[qq*4];
      float tv[12];
      #pragma unroll
      for (int qq = 0; qq < 4; ++qq) {
        tv[qq*3+0] = b2f((unsigned short)(w4[qq]));
        tv[qq*3+1] = b2f((unsigned short)(w4[qq] >> 16));
        tv[qq*3+2] = b2f((unsigned short)(w4[qq] >> 32));
      }
      const int xb = wv*768 + lane*12;
      float xv2[12];
      float ssqT = 0.f, ssqX = 0.f;
      #pragma unroll
      for (int i = 0; i < 12; ++i) {
        float xx = sX2[xb + i];
        const float tt = tv[i];
        #pragma unroll
        for (int rr = 0; rr < 10; ++rr) xx = 0.5f*xx + 0.5f*tt;
        sX2[xb + i] = xx; xv2[i] = xx;
        ssqT += tt*tt; ssqX += xx*xx;
      }
      ssqT = wsum(ssqT); ssqX = wsum(ssqX);
      const float invT = 1.0f / fmaxf(sqrtf(ssqT), 1e-12f);
      const float invX = 1.0f / fmaxf(sqrtf(ssqX), 1e-12f);
      #pragma unroll
      for (int i = 0; i < 12; ++i) sX[xb + i] = 0.5f*(tv[i]*invT + xv2[i]*invX);
      __syncthreads();
      const int ks = lane, isub = wv;
      float acc[3][4] = {};
      #pragma unroll
      for (int ip = 0; ip < 3; ++ip) {
        const int k = ks + 64*(isub + 4*ip);
        float xv[4];
        #pragma unroll
        for (int bb = 0; bb < 4; ++bb) xv[bb] = sX[bb*768 + k];
        #pragma unroll
        for (int c = 0; c < 3; ++c) {
          const float w = sW1[c*768 + k];
          acc[c][0] += w*xv[0]; acc[c][1] += w*xv[1]; acc[c][2] += w*xv[2]; acc[c][3] += w*xv[3];
        }
      }
      #pragma unroll
      for (int c = 0; c < 3; ++c)
        #pragma unroll
        for (int bb = 0; bb < 4; ++bb) {
          const float v = wsum(acc[c][bb]);
          if (lane == 0) sRed[isub*12 + c*4 + bb] = v;
        }
      __syncthreads();
      if (tid < 4) {
        const int bb = tid;
        float v[3];
        #pragma unroll
        for (int c = 0; c < 3; ++c) {
          float s = sRed[c*4+bb] + sRed[12 + c*4+bb] + sRed[24 + c*4+bb] + sRed[36 + c*4+bb];
          v[c] = geluf(s + sCst[3 + c]);
        }
        st64(u_if + (size_t)t*1024 + g*4 + bb, pk3t(v[0], v[1], v[2], tagp));
      }
      vm0();
      __syncthreads();
      if (tid == 0) stflag(flg + F0(2, g), want);
    }

    // ================= P4: cf/gv -> fused pre-LN slice =================
    {
      if (isAgg) {
        if (tid < 16)
          while (ldflag(flg + F0(2, g*16 + tid)) < want) __builtin_amdgcn_s_sleep(2);
        __syncthreads();
        if (tid == 0) stflag(flg + F1(2, g), want);
      }
      if (tid < 16)
        while (ldflag(flg + F1(2, tid)) < want) __builtin_amdgcn_s_sleep(8);
      __syncthreads();
      const u64* pm = u_if + (size_t)t*1024 + lane*16 + wv;
      u64 w4[4];
      #pragma unroll
      for (int qq = 0; qq < 4; ++qq) w4[qq] = pm[qq*4];
      const int xb = wv*768 + lane*12;
      #pragma unroll
      for (int qq = 0; qq < 4; ++qq) {
        sX[xb + qq*3 + 0] = b2f((unsigned short)(w4[qq]));
        sX[xb + qq*3 + 1] = b2f((unsigned short)(w4[qq] >> 16));
        sX[xb + qq*3 + 2] = b2f((unsigned short)(w4[qq] >> 32));
      }
      __syncthreads();
      const int ks = lane, isub = wv;
      float acc[6][4] = {};
      #pragma unroll
      for (int ip = 0; ip < 3; ++ip) {
        const int k = ks + 64*(isub + 4*ip);
        float xv[4];
        #pragma unroll
        for (int bb = 0; bb < 4; ++bb) xv[bb] = sX[bb*768 + k];
        #pragma unroll
        for (int c = 0; c < 6; ++c) {
          const float w = (c < 3) ? sW2[c*768 + k] : sW2G[(c-3)*768 + k];
          acc[c][0] += w*xv[0]; acc[c][1] += w*xv[1]; acc[c][2] += w*xv[2]; acc[c][3] += w*xv[3];
        }
      }
      #pragma unroll
      for (int c = 0; c < 6; ++c)
        #pragma unroll
        for (int bb = 0; bb < 4; ++bb) {
          const float v = wsum(acc[c][bb]);
          if (lane == 0) sRed[isub*24 + c*4 + bb] = v;
        }
      __syncthreads();
      if (tid < 4) {
        const int bb = tid;
        float pre3[3];
        #pragma unroll
        for (int c = 0; c < 3; ++c) {
          float sc = sRed[c*4+bb] + sRed[24 + c*4+bb] + sRed[48 + c*4+bb] + sRed[72 + c*4+bb];
          const float cf = sc + sCst[6 + c];
          const int cc = c + 3;
          float sg = sRed[cc*4+bb] + sRed[24 + cc*4+bb] + sRed[48 + cc*4+bb] + sRed[72 + cc*4+bb];
          const float gv = sg + sEWg[c*4 + bb] + sCst[9 + c];
          const float gg = 1.0f / (1.0f + expf(-gv));
          const float em = sEmb[c*4 + bb];
          pre3[c] = gg*(cf + 0.4f*sTf[c*4 + bb]) + (1.0f - gg)*em;
        }
        st64(pre_if + (size_t)t*1024 + g*4 + bb, pk3t(pre3[0], pre3[1], pre3[2], tagp));
      }
      vm0();
      __syncthreads();
      if (tid == 0) stflag(flg + F0(3, g), want);
    }
  }
}

// ---------------------------------------------------------------------------
// host
// ---------------------------------------------------------------------------
static void launch_gemm(const float* A, const void* B, float* C, const float* bias,
                        int M, int N, int bmode, hipStream_t st)
{
  const int ntiles = (N + 63) / 64;
  const int q = ntiles / 8, r = ntiles % 8;
  const int mtiles = M / 64;
  const int smax = (q + (r ? 1 : 0)) * mtiles;
  dim3 grid(8, smax);
  if (bmode == 0) gemm_kernel<0><<<grid, 256, 0, st>>>(A, B, C, bias, M, N, q, r);
  else            gemm_kernel<1><<<grid, 256, 0, st>>>(A, B, C, bias, M, N, q, r);
}

extern "C" void kernel_launch(void* const* d_in, const int* in_sizes, int n_in,
                              void* d_out, int out_size, void* d_ws, size_t ws_size,
                              hipStream_t stream)
{
  const int*   tok   = (const int*)d_in[0];
  const float* emb   = (const float*)d_in[1];
  const float* V0    = (const float*)d_in[2];
  const float* b0    = (const float*)d_in[3];
  const float* V1    = (const float*)d_in[4];
  const float* b1    = (const float*)d_in[5];
  const float* W1    = (const float*)d_in[6];
  const float* c1    = (const float*)d_in[7];
  const float* W2    = (const float*)d_in[8];
  const float* c2    = (const float*)d_in[9];
  const float* Wg    = (const float*)d_in[10];
  const float* bg    = (const float*)d_in[11];
  const float* Wt    = (const float*)d_in[12];
  const float* gamma = (const float*)d_in[13];
  const float* beta  = (const float*)d_in[14];
  const float* Wl    = (const float*)d_in[15];
  const float* Rw    = (const float*)d_in[16];

  float* outf = (float*)d_out;
  // scratch carved from d_out (all consumed before the final GEMM overwrites)
  float* emb_all = outf + 0;                    //  786432
  float* RV0     = outf + 786432;               // 2359296
  float* RWt     = outf + 3145728;              //  589824
  float* W2G     = outf + 3735552;              //  589824
  float* embV0   = outf + 4325376;              // 3145728
  float* embWg   = outf + 7471104;              //  786432
  float* gbias   = outf + 8257536;              //    1024
  unsigned short* V0T  = (unsigned short*)(outf + 8258560);   // 2359296 el
  unsigned short* WtT  = (unsigned short*)(outf + 9438208);   //  589824 el
  unsigned short* WgTT = (unsigned short*)(outf + 9733120);   //  589824 el
  unsigned short* WgBT = (unsigned short*)(outf + 10028032);  //  589824 el
  u64* a1_if  = (u64*)(outf + 10322944);  // 257*4096 u64 -> 2105344 f
  u64* tg_if  = (u64*)(outf + 12428288);  // 257*1024 u64 ->  526336 f
  u64* u_if   = (u64*)(outf + 12954624);
  u64* pre_if = (u64*)(outf + 13480960);
  int* flg    = (int*)(outf + 14007296);  // 17408 ints (padded flag0+flag1)
                                          // end 14024704 < 51463168

  float* h_all = (float*)d_ws;                                // 786432 f32
  unsigned short* WlT = (unsigned short*)((char*)d_ws + 786432*4);
  const bool bigws = ws_size >= (size_t)(786432*4) + (size_t)38597376*2 + 256;

  hipMemsetAsync(flg, 0, 17408 * sizeof(int), stream);

  // transposed bf16 copies of GEMM B operands
  transpose_f2b<<<dim3(96, 24),   256, 0, stream>>>(V0, V0T, 3072, 0);
  transpose_f2b<<<dim3(24, 24),   256, 0, stream>>>(Wt, WtT, 768, 0);
  transpose_f2b<<<dim3(24, 24),   256, 0, stream>>>(Wg, WgTT, 768, 0);
  transpose_f2b<<<dim3(24, 24),   256, 0, stream>>>(Wg, WgBT, 768, 768);
  if (bigws)
    transpose_f2b<<<dim3(1572, 24), 256, 0, stream>>>(Wl, WlT, 50257, 0);

  embed_kernel<<<1024, 256, 0, stream>>>(tok, emb, emb_all);
  gbias_kernel<<<3, 256, 0, stream>>>(c2, Wg, gbias);

  // fused-weight + per-token precompute GEMMs (bf16 MFMA, fp32 out)
  launch_gemm(Rw,      V0T,  RV0,   nullptr, 768,  3072, 0, stream);
  launch_gemm(Rw,      WtT,  RWt,   nullptr, 768,  768,  0, stream);
  launch_gemm(W2,      WgBT, W2G,   nullptr, 768,  768,  0, stream);
  launch_gemm(emb_all, V0T,  embV0, b0,      1024, 3072, 0, stream);
  launch_gemm(emb_all, WgTT, embWg, bg,      1024, 768,  0, stream);

  // the sequential part
  recur_kernel<<<256, 256, 0, stream>>>(
      RV0, RWt, W1, W2, W2G, V1, embV0, embWg, gbias, emb_all,
      b1, c1, c2, gamma, beta, h_all,
      a1_if, tg_if, u_if, pre_if, flg);

  // deferred lm_head: logits[b*256+t][v] = h_all @ Wl
  if (bigws) launch_gemm(h_all, WlT, outf, nullptr, 1024, 50257, 0, stream);
  else       launch_gemm(h_all, Wl,  outf, nullptr, 1024, 50257, 1, stream);
}

// Round 10
// 8392.159 us; speedup vs baseline: 4.5749x; 1.0448x over previous
//
#include <hip/hip_runtime.h>

// ============================================================================
// AgnisV5: sequential recurrence (4-phase persistent kernel, weights in LDS)
//          + deferred batched lm_head GEMM (bf16 MFMA).
//
// Round-9 change: TAGGED FIRE-AND-FORGET RELEASE (2-hop sync). R8's chain had
// 3 serial fabric transactions per phase (payload-ack via vmcnt(0), flag0,
// flag1). Now payload words carry their own validity (R3's proven 3xbf16+tag
// u64); producers just store and move on. The 16 aggregator WGs poll their
// group's payload TAG WORDS directly (one dedicated thread per word -> H4
// per-line discipline), then store the padded flag1 line. Consumers poll the
// 16 flag1 lines (R8 pattern) and plain-load the payload (R6 L2-fanout:
// write-once step-indexed buffers; flag1 set only after ALL words reached
// IF$, so a first-per-XCD L2 miss fetches fresh lines).
// Also: x2 EMA closed form x2 = t + (x2-t)*2^-10 (== 10 iterations), dead
// emb preloads removed, P4-end barrier added (prefetch WAR protection).
// ============================================================================

typedef __attribute__((ext_vector_type(8))) short short8;
typedef __attribute__((ext_vector_type(4))) float f32x4;
typedef unsigned long long u64;

__device__ __forceinline__ unsigned short f2b(float f){
  unsigned int u = __builtin_bit_cast(unsigned int, f);
  u += 0x7fffu + ((u >> 16) & 1u);
  return (unsigned short)(u >> 16);
}
__device__ __forceinline__ float b2f(unsigned short v){
  return __builtin_bit_cast(float, ((unsigned int)v) << 16);
}
__device__ __forceinline__ float geluf(float x){
  return 0.5f * x * (1.0f + erff(x * 0.70710678118654752440f));
}
__device__ __forceinline__ float wsum(float v){
  #pragma unroll
  for (int o = 32; o; o >>= 1) v += __shfl_xor(v, o, 64);
  return v;
}
__device__ __forceinline__ u64 pk3t(float a, float b, float c, unsigned tag){
  return (u64)f2b(a) | ((u64)f2b(b) << 16) | ((u64)f2b(c) << 32) | ((u64)(tag & 0xffffu) << 48);
}
// sc1 (IF$-coherent) accessors — the only cross-XCD-visible ops we use
__device__ __forceinline__ void st64(u64* p, u64 v){
  __hip_atomic_store(p, v, __ATOMIC_RELAXED, __HIP_MEMORY_SCOPE_AGENT);
}
__device__ __forceinline__ u64 ld64(const u64* p){
  return __hip_atomic_load(p, __ATOMIC_RELAXED, __HIP_MEMORY_SCOPE_AGENT);
}
__device__ __forceinline__ void stflag(int* p, int v){
  __hip_atomic_store(p, v, __ATOMIC_RELAXED, __HIP_MEMORY_SCOPE_AGENT);
}
__device__ __forceinline__ int ldflag(const int* p){
  return __hip_atomic_load(p, __ATOMIC_RELAXED, __HIP_MEMORY_SCOPE_AGENT);
}
// wait until word's tag (bits 48..63) equals want (write-once buffers:
// terminates because the slot's unique write carries exactly this tag)
__device__ __forceinline__ void waittag(const u64* p, unsigned want){
  while ((unsigned)(ld64(p) >> 48) != (want & 0xffffu)) __builtin_amdgcn_s_sleep(2);
}

// flag1: 4 phases x 16 aggregators, each on its own 64B line
#define F1(ph,a) ((((ph)*16) + (a))*16)
// phases: 0=A1, 1=TG, 2=U, 3=PRE

// ---------------------------------------------------------------------------
// transpose + f32->bf16 : src [768, N] (rows offset by rowoff) -> dst [N, 768]
// ---------------------------------------------------------------------------
__global__ __launch_bounds__(256) void transpose_f2b(
    const float* __restrict__ src, unsigned short* __restrict__ dst,
    int N, int rowoff)
{
  __shared__ unsigned short tile[32][33];
  const int nb = blockIdx.x * 32, kb = blockIdx.y * 32;
  const int tx = threadIdx.x & 31, ty = threadIdx.x >> 5;
  #pragma unroll
  for (int i = 0; i < 4; ++i) {
    int k = kb + ty + 8*i, n = nb + tx;
    unsigned short v = 0;
    if (n < N) v = f2b(src[(size_t)(rowoff + k)*N + n]);
    tile[ty + 8*i][tx] = v;
  }
  __syncthreads();
  #pragma unroll
  for (int i = 0; i < 4; ++i) {
    int n = nb + ty + 8*i;
    if (n < N) dst[(size_t)n*768 + kb + tx] = tile[tx][ty + 8*i];
  }
}

// ---------------------------------------------------------------------------
// embedding gather + L2 normalize : emb_all[b*256+t][768]
// ---------------------------------------------------------------------------
__global__ __launch_bounds__(256) void embed_kernel(
    const int* __restrict__ tok, const float* __restrict__ emb,
    float* __restrict__ emb_all)
{
  const int row = blockIdx.x, tid = threadIdx.x;
  const int id = tok[row];
  const float* e = emb + (size_t)id * 768;
  float v0 = e[tid], v1 = e[tid+256], v2 = e[tid+512];
  float ssq = wsum(v0*v0 + v1*v1 + v2*v2);
  __shared__ float red[4];
  if ((tid & 63) == 0) red[tid >> 6] = ssq;
  __syncthreads();
  float inv = 1.0f / fmaxf(sqrtf(red[0]+red[1]+red[2]+red[3]), 1e-12f);
  float* o = emb_all + (size_t)row * 768;
  o[tid] = v0*inv; o[tid+256] = v1*inv; o[tid+512] = v2*inv;
}

// gbias[c] = sum_k c2[k] * Wg[768+k][c]
__global__ void gbias_kernel(const float* __restrict__ c2,
                             const float* __restrict__ Wg,
                             float* __restrict__ gbias)
{
  int c = blockIdx.x * 256 + threadIdx.x;
  if (c >= 768) return;
  float s = 0.f;
  for (int k = 0; k < 768; ++k) s += c2[k] * Wg[(size_t)(768 + k)*768 + c];
  gbias[c] = s;
}

// ---------------------------------------------------------------------------
// GEMM: C[M,N] = A[M,768](f32, bf16-cast) @ B + bias
//   BMODE 0: B = BT bf16 [N,768] (transposed)   BMODE 1: B = f32 [768,N]
// ---------------------------------------------------------------------------
template<int BMODE>
__global__ __launch_bounds__(256) void gemm_kernel(
    const float* __restrict__ A, const void* __restrict__ Bp,
    float* __restrict__ C, const float* __restrict__ bias,
    int M, int N, int q, int r)
{
  const int x = blockIdx.x;
  const int s = blockIdx.y;
  const int mtiles = M >> 6;
  const int cnt_x = q + (x < r ? 1 : 0);
  if (s >= cnt_x * mtiles) return;
  const int off_x = x*q + (x < r ? x : r);
  const int nt = off_x + s / mtiles;
  const int mt = s % mtiles;
  const int m0 = mt << 6, n0 = nt << 6;
  const int w = threadIdx.x >> 6, l = threadIdx.x & 63;
  const int lrow = l & 15, lk8 = (l >> 4) << 3;
  const int arow = m0 + w*16 + lrow;
  f32x4 acc[4] = {f32x4{0,0,0,0}, f32x4{0,0,0,0}, f32x4{0,0,0,0}, f32x4{0,0,0,0}};
  const unsigned short* BT = (const unsigned short*)Bp;
  const float* Bf = (const float*)Bp;

  for (int kk = 0; kk < 768; kk += 32) {
    const float4* ap = (const float4*)(A + (size_t)arow*768 + kk + lk8);
    float4 a0 = ap[0], a1 = ap[1];
    short8 af;
    af[0]=(short)f2b(a0.x); af[1]=(short)f2b(a0.y); af[2]=(short)f2b(a0.z); af[3]=(short)f2b(a0.w);
    af[4]=(short)f2b(a1.x); af[5]=(short)f2b(a1.y); af[6]=(short)f2b(a1.z); af[7]=(short)f2b(a1.w);
    #pragma unroll
    for (int ss = 0; ss < 4; ++ss) {
      const int col = n0 + ss*16 + lrow;
      short8 bf;
      if (BMODE == 0) {
        if (col < N) {
          uint4 raw = *(const uint4*)(BT + (size_t)col*768 + kk + lk8);
          bf = __builtin_bit_cast(short8, raw);
        } else {
          bf = short8{0,0,0,0,0,0,0,0};
        }
      } else {
        #pragma unroll
        for (int j = 0; j < 8; ++j) {
          float v = (col < N) ? Bf[(size_t)(kk + lk8 + j)*N + col] : 0.f;
          bf[j] = (short)f2b(v);
        }
      }
      acc[ss] = __builtin_amdgcn_mfma_f32_16x16x32_bf16(af, bf, acc[ss], 0, 0, 0);
    }
  }
  const int rbase = m0 + w*16 + ((l >> 4) << 2);
  #pragma unroll
  for (int ss = 0; ss < 4; ++ss) {
    const int col = n0 + ss*16 + lrow;
    if (col < N) {
      const float badd = bias ? bias[col] : 0.f;
      #pragma unroll
      for (int rr = 0; rr < 4; ++rr)
        C[(size_t)(rbase + rr)*N + col] = acc[ss][rr] + badd;
    }
  }
}

// ---------------------------------------------------------------------------
// Persistent recurrent kernel: 256 WGs (1/CU), 256 threads.
// WG g owns cols [g*12,+12) of RV0 and [g*3,+3) of V1/W1/W2/W2G/RWt in LDS.
//   a1_if : [257 t][4 bb][1024 w] u64 tagged, word j = cols 3j..3j+2
//   tg/u/pre_if : [257 t][1024 w] u64 tagged, word = G*4+bb -> cols G*3..+2
// Aggregator a (WG a<16) covers producers [a*16, a*16+16).
// ---------------------------------------------------------------------------
__global__ __launch_bounds__(256) void recur_kernel(
    const float* __restrict__ RV0, const float* __restrict__ RWt,
    const float* __restrict__ W1,  const float* __restrict__ W2,
    const float* __restrict__ W2G, const float* __restrict__ V1,
    const float* __restrict__ embV0, const float* __restrict__ embWg,
    const float* __restrict__ gbias, const float* __restrict__ emb_all,
    const float* __restrict__ b1, const float* __restrict__ c1,
    const float* __restrict__ c2, const float* __restrict__ gam,
    const float* __restrict__ bet, float* __restrict__ h_all,
    u64* __restrict__ a1_if, u64* __restrict__ tg_if,
    u64* __restrict__ u_if,  u64* __restrict__ pre_if,
    int* __restrict__ flg)
{
  __shared__ float sRV0[12*768];        // 36864 B
  __shared__ float sV1[3*3072];         // 36864 B
  __shared__ float sW1[3*768];
  __shared__ float sW2[3*768];
  __shared__ float sW2G[3*768];
  __shared__ float sRWt[3*768];         // 4 x 9216 B
  __shared__ float sX[4*768];           // 12288 B
  __shared__ float sX2[4*768];          // 12288 B
  __shared__ unsigned short sA1[4*3072];// 24576 B
  __shared__ float sRed[240];           // 960 B
  __shared__ float sTf[16];             // 64 B
  __shared__ float sCst[12];            // b1/c1/c2/gbias slices (step-invariant)
  __shared__ float sEV0[48];            // embV0 step-t slice (prefetched)
  __shared__ float sEWg[12];            // embWg step-t slice
  __shared__ float sEmb[12];            // emb_all step-t slice (P4)

  const int g = blockIdx.x, tid = threadIdx.x;
  const int wv = tid >> 6, lane = tid & 63;
  const bool isAgg = (g < 16);

  // ---- load weight slices into LDS ----
  for (int i = tid; i < 12*768; i += 256) {
    int k = i / 12, c = i - k*12;
    sRV0[c*768 + k] = RV0[(size_t)k*3072 + g*12 + c];
  }
  for (int i = tid; i < 3*3072; i += 256) {
    int k = i / 3, c = i - k*3;
    sV1[c*3072 + k] = V1[(size_t)k*768 + g*3 + c];
  }
  for (int i = tid; i < 3*768; i += 256) {
    int k = i / 3, c = i - k*3;
    const int gc = g*3 + c;
    sW1[c*768 + k]  = W1[(size_t)k*768 + gc];
    sW2[c*768 + k]  = W2[(size_t)k*768 + gc];
    sW2G[c*768 + k] = W2G[(size_t)k*768 + gc];
    sRWt[c*768 + k] = RWt[(size_t)k*768 + gc];
  }
  for (int i = tid; i < 4*768; i += 256) sX2[i] = 0.f;
  // step-invariant per-WG constants
  if (tid < 3)       sCst[tid]     = b1[g*3 + tid];
  else if (tid < 6)  sCst[tid]     = c1[g*3 + tid - 3];
  else if (tid < 9)  sCst[tid]     = c2[g*3 + tid - 6];
  else if (tid < 12) sCst[tid]     = gbias[g*3 + tid - 9];
  // step-invariant LN params (per-thread registers)
  const int k0 = lane*12;
  float gamv[12], betv[12];
  #pragma unroll
  for (int i = 0; i < 12; ++i) { gamv[i] = gam[k0+i]; betv[i] = bet[k0+i]; }
  __syncthreads();

  for (int t = 0; t <= 256; ++t) {
    // ---- prefetch step-t token slices (idle waves; overlaps h-phase sync) --
    if (t < 256) {
      if (tid >= 64 && tid < 112) {
        const int j = tid - 64, bb = j & 3, c = j >> 2;   // c 0..11
        sEV0[c*4 + bb] = embV0[(size_t)(bb*256 + t)*3072 + g*12 + c];
      } else if (tid >= 128 && tid < 140) {
        const int j = tid - 128, bb = j & 3, c = j >> 2;  // c 0..2
        sEWg[c*4 + bb] = embWg[(size_t)(bb*256 + t)*768 + g*3 + c];
      } else if (tid >= 140 && tid < 152) {
        const int j = tid - 140, bb = j & 3, c = j >> 2;
        sEmb[c*4 + bb] = emb_all[(size_t)(bb*256 + t)*768 + g*3 + c];
      }
    }

    // ================= h_{t-1} from fused pre-LN words =================
    if (t == 0) {
      for (int i = tid; i < 4*768; i += 256) sX[i] = 0.f;
    } else {
      // 2-hop sync on PRE: agg detects payload tags, consumers poll flag1
      if (isAgg) {
        if (tid < 64)
          waittag(pre_if + (size_t)(t-1)*1024 + (g*16 + (tid >> 2))*4 + (tid & 3),
                  (unsigned)t);
        __syncthreads();
        if (tid == 0) stflag(flg + F1(3, g), t);
      }
      if (tid < 16)
        while (ldflag(flg + F1(3, tid)) < t) __builtin_amdgcn_s_sleep(8);
      __syncthreads();
      const u64* pm = pre_if + (size_t)(t-1)*1024 + lane*16 + wv;
      u64 w4[4];
      #pragma unroll
      for (int qq = 0; qq < 4; ++qq) w4[qq] = pm[qq*4];   // plain, L2-served
      float pre[12];
      #pragma unroll
      for (int qq = 0; qq < 4; ++qq) {
        pre[qq*3+0] = b2f((unsigned short)(w4[qq]));
        pre[qq*3+1] = b2f((unsigned short)(w4[qq] >> 16));
        pre[qq*3+2] = b2f((unsigned short)(w4[qq] >> 32));
      }
      float s1 = 0.f;
      #pragma unroll
      for (int i = 0; i < 12; ++i) s1 += pre[i];
      s1 = wsum(s1);
      const float mean = s1 * (1.0f/768.0f);
      float s2 = 0.f;
      #pragma unroll
      for (int i = 0; i < 12; ++i) { const float d = pre[i] - mean; s2 += d*d; }
      s2 = wsum(s2);
      const float rstd = 1.0f / sqrtf(s2*(1.0f/768.0f) + 1e-5f);
      float hv[12];
      #pragma unroll
      for (int i = 0; i < 12; ++i) {
        hv[i] = (pre[i] - mean)*rstd*gamv[i] + betv[i];
        sX[wv*768 + k0 + i] = hv[i];
      }
      if (g == 0) {
        float* hp = h_all + (size_t)(wv*256 + t - 1)*768 + k0;
        #pragma unroll
        for (int i = 0; i < 12; ++i) hp[i] = hv[i];
      }
    }
    __syncthreads();
    if (t == 256) break;
    const unsigned tagp = (unsigned)(t + 1);
    const int want = t + 1;

    // ================= P1: a1 slice (12 cols), tf slice (LDS stash) ========
    {
      const int cg = tid >> 6, ks = tid & 63;
      float acc[4][4] = {};
      for (int i = 0; i < 12; ++i) {
        const int k = ks + 64*i;
        const float x0 = sX[k], x1 = sX[768+k], x2v = sX[1536+k], x3 = sX[2304+k];
        #pragma unroll
        for (int j = 0; j < 4; ++j) {
          float w;
          if (cg < 3) w = sRV0[(cg*4 + j)*768 + k];
          else        w = (j < 3) ? sRWt[j*768 + k] : 0.f;
          acc[j][0] += w*x0; acc[j][1] += w*x1; acc[j][2] += w*x2v; acc[j][3] += w*x3;
        }
      }
      #pragma unroll
      for (int j = 0; j < 4; ++j)
        #pragma unroll
        for (int bb = 0; bb < 4; ++bb) {
          const float v = wsum(acc[j][bb]);
          if (lane == 0) sRed[cg*16 + j*4 + bb] = v;
        }
      __syncthreads();
      if (tid < 16) {               // 16 tagged a1 words, fire-and-forget
        const int bb = tid & 3, w = tid >> 2;
        float v[3];
        #pragma unroll
        for (int s = 0; s < 3; ++s) {
          const int c = w*3 + s;    // 0..11
          const float raw = sRed[(c >> 2)*16 + (c & 3)*4 + bb];
          v[s] = geluf(sEV0[c*4 + bb] + 0.4f*raw);
        }
        st64(a1_if + (size_t)t*4096 + bb*1024 + g*4 + w, pk3t(v[0], v[1], v[2], tagp));
      } else if (tid < 20) {        // stash tf slice for P4's fused pre
        const int bb = tid - 16;
        sTf[bb]     = sRed[48 + bb];
        sTf[4 + bb] = sRed[52 + bb];
        sTf[8 + bb] = sRed[56 + bb];
      }
    }

    // ================= P2: target slice =================
    {
      if (isAgg) {                  // detect all 16 words of my 16 producers
        waittag(a1_if + (size_t)t*4096 + ((tid & 15) >> 2)*1024
                      + (g*16 + (tid >> 4))*4 + (tid & 3), tagp);
        __syncthreads();
        if (tid == 0) stflag(flg + F1(0, g), want);
      }
      if (tid < 16)
        while (ldflag(flg + F1(0, tid)) < want) __builtin_amdgcn_s_sleep(8);
      __syncthreads();
      const u64* basep = a1_if + (size_t)t*4096;
      u64 x[16];
      #pragma unroll
      for (int i = 0; i < 16; ++i) x[i] = basep[i*256 + tid];  // plain, coalesced
      #pragma unroll
      for (int i = 0; i < 16; ++i) {
        const int widx = i*256 + tid;       // [0,4096)
        const int bb = widx >> 10, j = widx & 1023;
        sA1[bb*3072 + 3*j + 0] = (unsigned short)(x[i]);
        sA1[bb*3072 + 3*j + 1] = (unsigned short)(x[i] >> 16);
        sA1[bb*3072 + 3*j + 2] = (unsigned short)(x[i] >> 32);
      }
      __syncthreads();
      const int ks = lane, isub = wv;
      float acc[3][4] = {};
      for (int ip = 0; ip < 12; ++ip) {
        const int k = ks + 64*(isub + 4*ip);
        float xv[4];
        #pragma unroll
        for (int bb = 0; bb < 4; ++bb) xv[bb] = b2f(sA1[bb*3072 + k]);
        #pragma unroll
        for (int c = 0; c < 3; ++c) {
          const float w = sV1[c*3072 + k];
          acc[c][0] += w*xv[0]; acc[c][1] += w*xv[1]; acc[c][2] += w*xv[2]; acc[c][3] += w*xv[3];
        }
      }
      #pragma unroll
      for (int c = 0; c < 3; ++c)
        #pragma unroll
        for (int bb = 0; bb < 4; ++bb) {
          const float v = wsum(acc[c][bb]);
          if (lane == 0) sRed[isub*12 + c*4 + bb] = v;
        }
      __syncthreads();
      if (tid < 4) {
        const int bb = tid;
        float v[3];
        #pragma unroll
        for (int c = 0; c < 3; ++c) {
          float s = sRed[c*4+bb] + sRed[12 + c*4+bb] + sRed[24 + c*4+bb] + sRed[36 + c*4+bb];
          v[c] = geluf(s + sCst[c]);
        }
        st64(tg_if + (size_t)t*1024 + g*4 + bb, pk3t(v[0], v[1], v[2], tagp));
      }
    }

    // ================= P3: x2 EMA, cb, u slice =================
    {
      if (isAgg) {
        if (tid < 64)
          waittag(tg_if + (size_t)t*1024 + (g*16 + (tid >> 2))*4 + (tid & 3), tagp);
        __syncthreads();
        if (tid == 0) stflag(flg + F1(1, g), want);
      }
      if (tid < 16)
        while (ldflag(flg + F1(1, tid)) < want) __builtin_amdgcn_s_sleep(8);
      __syncthreads();
      const u64* pm = tg_if + (size_t)t*1024 + lane*16 + wv;
      u64 w4[4];
      #pragma unroll
      for (int qq = 0; qq < 4; ++qq) w4[qq] = pm[qq*4];
      float tv[12];
      #pragma unroll
      for (int qq = 0; qq < 4; ++qq) {
        tv[qq*3+0] = b2f((unsigned short)(w4[qq]));
        tv[qq*3+1] = b2f((unsigned short)(w4[qq] >> 16));
        tv[qq*3+2] = b2f((unsigned short)(w4[qq] >> 32));
      }
      const int xb = wv*768 + lane*12;
      float xv2[12];
      float ssqT = 0.f, ssqX = 0.f;
      #pragma unroll
      for (int i = 0; i < 12; ++i) {
        const float tt = tv[i];
        // closed form of 10x {x = 0.5x + 0.5t}: x = t + (x-t)*2^-10
        const float xx = tt + (sX2[xb + i] - tt) * 0.0009765625f;
        sX2[xb + i] = xx; xv2[i] = xx;
        ssqT += tt*tt; ssqX += xx*xx;
      }
      ssqT = wsum(ssqT); ssqX = wsum(ssqX);
      const float invT = 1.0f / fmaxf(sqrtf(ssqT), 1e-12f);
      const float invX = 1.0f / fmaxf(sqrtf(ssqX), 1e-12f);
      #pragma unroll
      for (int i = 0; i < 12; ++i) sX[xb + i] = 0.5f*(tv[i]*invT + xv2[i]*invX);
      __syncthreads();
      const int ks = lane, isub = wv;
      float acc[3][4] = {};
      #pragma unroll
      for (int ip = 0; ip < 3; ++ip) {
        const int k = ks + 64*(isub + 4*ip);
        float xv[4];
        #pragma unroll
        for (int bb = 0; bb < 4; ++bb) xv[bb] = sX[bb*768 + k];
        #pragma unroll
        for (int c = 0; c < 3; ++c) {
          const float w = sW1[c*768 + k];
          acc[c][0] += w*xv[0]; acc[c][1] += w*xv[1]; acc[c][2] += w*xv[2]; acc[c][3] += w*xv[3];
        }
      }
      #pragma unroll
      for (int c = 0; c < 3; ++c)
        #pragma unroll
        for (int bb = 0; bb < 4; ++bb) {
          const float v = wsum(acc[c][bb]);
          if (lane == 0) sRed[isub*12 + c*4 + bb] = v;
        }
      __syncthreads();
      if (tid < 4) {
        const int bb = tid;
        float v[3];
        #pragma unroll
        for (int c = 0; c < 3; ++c) {
          float s = sRed[c*4+bb] + sRed[12 + c*4+bb] + sRed[24 + c*4+bb] + sRed[36 + c*4+bb];
          v[c] = geluf(s + sCst[3 + c]);
        }
        st64(u_if + (size_t)t*1024 + g*4 + bb, pk3t(v[0], v[1], v[2], tagp));
      }
    }

    // ================= P4: cf/gv -> fused pre-LN slice =================
    {
      if (isAgg) {
        if (tid < 64)
          waittag(u_if + (size_t)t*1024 + (g*16 + (tid >> 2))*4 + (tid & 3), tagp);
        __syncthreads();
        if (tid == 0) stflag(flg + F1(2, g), want);
      }
      if (tid < 16)
        while (ldflag(flg + F1(2, tid)) < want) __builtin_amdgcn_s_sleep(8);
      __syncthreads();
      const u64* pm = u_if + (size_t)t*1024 + lane*16 + wv;
      u64 w4[4];
      #pragma unroll
      for (int qq = 0; qq < 4; ++qq) w4[qq] = pm[qq*4];
      const int xb = wv*768 + lane*12;
      #pragma unroll
      for (int qq = 0; qq < 4; ++qq) {
        sX[xb + qq*3 + 0] = b2f((unsigned short)(w4[qq]));
        sX[xb + qq*3 + 1] = b2f((unsigned short)(w4[qq] >> 16));
        sX[xb + qq*3 + 2] = b2f((unsigned short)(w4[qq] >> 32));
      }
      __syncthreads();
      const int ks = lane, isub = wv;
      float acc[6][4] = {};
      #pragma unroll
      for (int ip = 0; ip < 3; ++ip) {
        const int k = ks + 64*(isub + 4*ip);
        float xv[4];
        #pragma unroll
        for (int bb = 0; bb < 4; ++bb) xv[bb] = sX[bb*768 + k];
        #pragma unroll
        for (int c = 0; c < 6; ++c) {
          const float w = (c < 3) ? sW2[c*768 + k] : sW2G[(c-3)*768 + k];
          acc[c][0] += w*xv[0]; acc[c][1] += w*xv[1]; acc[c][2] += w*xv[2]; acc[c][3] += w*xv[3];
        }
      }
      #pragma unroll
      for (int c = 0; c < 6; ++c)
        #pragma unroll
        for (int bb = 0; bb < 4; ++bb) {
          const float v = wsum(acc[c][bb]);
          if (lane == 0) sRed[isub*24 + c*4 + bb] = v;
        }
      __syncthreads();
      if (tid < 4) {
        const int bb = tid;
        float pre3[3];
        #pragma unroll
        for (int c = 0; c < 3; ++c) {
          float sc = sRed[c*4+bb] + sRed[24 + c*4+bb] + sRed[48 + c*4+bb] + sRed[72 + c*4+bb];
          const float cf = sc + sCst[6 + c];
          const int cc = c + 3;
          float sg = sRed[cc*4+bb] + sRed[24 + cc*4+bb] + sRed[48 + cc*4+bb] + sRed[72 + cc*4+bb];
          const float gv = sg + sEWg[c*4 + bb] + sCst[9 + c];
          const float gg = 1.0f / (1.0f + expf(-gv));
          const float em = sEmb[c*4 + bb];
          pre3[c] = gg*(cf + 0.4f*sTf[c*4 + bb]) + (1.0f - gg)*em;
        }
        st64(pre_if + (size_t)t*1024 + g*4 + bb, pk3t(pre3[0], pre3[1], pre3[2], tagp));
      }
      __syncthreads();   // protect sEWg/sEmb against next-iter prefetch
    }
  }
}

// ---------------------------------------------------------------------------
// host
// ---------------------------------------------------------------------------
static void launch_gemm(const float* A, const void* B, float* C, const float* bias,
                        int M, int N, int bmode, hipStream_t st)
{
  const int ntiles = (N + 63) / 64;
  const int q = ntiles / 8, r = ntiles % 8;
  const int mtiles = M / 64;
  const int smax = (q + (r ? 1 : 0)) * mtiles;
  dim3 grid(8, smax);
  if (bmode == 0) gemm_kernel<0><<<grid, 256, 0, st>>>(A, B, C, bias, M, N, q, r);
  else            gemm_kernel<1><<<grid, 256, 0, st>>>(A, B, C, bias, M, N, q, r);
}

extern "C" void kernel_launch(void* const* d_in, const int* in_sizes, int n_in,
                              void* d_out, int out_size, void* d_ws, size_t ws_size,
                              hipStream_t stream)
{
  const int*   tok   = (const int*)d_in[0];
  const float* emb   = (const float*)d_in[1];
  const float* V0    = (const float*)d_in[2];
  const float* b0    = (const float*)d_in[3];
  const float* V1    = (const float*)d_in[4];
  const float* b1    = (const float*)d_in[5];
  const float* W1    = (const float*)d_in[6];
  const float* c1    = (const float*)d_in[7];
  const float* W2    = (const float*)d_in[8];
  const float* c2    = (const float*)d_in[9];
  const float* Wg    = (const float*)d_in[10];
  const float* bg    = (const float*)d_in[11];
  const float* Wt    = (const float*)d_in[12];
  const float* gamma = (const float*)d_in[13];
  const float* beta  = (const float*)d_in[14];
  const float* Wl    = (const float*)d_in[15];
  const float* Rw    = (const float*)d_in[16];

  float* outf = (float*)d_out;
  // scratch carved from d_out (all consumed before the final GEMM overwrites)
  float* emb_all = outf + 0;                    //  786432
  float* RV0     = outf + 786432;               // 2359296
  float* RWt     = outf + 3145728;              //  589824
  float* W2G     = outf + 3735552;              //  589824
  float* embV0   = outf + 4325376;              // 3145728
  float* embWg   = outf + 7471104;              //  786432
  float* gbias   = outf + 8257536;              //    1024
  unsigned short* V0T  = (unsigned short*)(outf + 8258560);   // 2359296 el
  unsigned short* WtT  = (unsigned short*)(outf + 9438208);   //  589824 el
  unsigned short* WgTT = (unsigned short*)(outf + 9733120);   //  589824 el
  unsigned short* WgBT = (unsigned short*)(outf + 10028032);  //  589824 el
  u64* a1_if  = (u64*)(outf + 10322944);  // 257*4096 u64 -> 2105344 f
  u64* tg_if  = (u64*)(outf + 12428288);  // 257*1024 u64 ->  526336 f
  u64* u_if   = (u64*)(outf + 12954624);
  u64* pre_if = (u64*)(outf + 13480960);
  int* flg    = (int*)(outf + 14007296);  // 1024 ints (flag1, padded lines)
                                          // end 14008320 < 51463168

  float* h_all = (float*)d_ws;                                // 786432 f32
  unsigned short* WlT = (unsigned short*)((char*)d_ws + 786432*4);
  const bool bigws = ws_size >= (size_t)(786432*4) + (size_t)38597376*2 + 256;

  hipMemsetAsync(flg, 0, 1024 * sizeof(int), stream);

  // transposed bf16 copies of GEMM B operands
  transpose_f2b<<<dim3(96, 24),   256, 0, stream>>>(V0, V0T, 3072, 0);
  transpose_f2b<<<dim3(24, 24),   256, 0, stream>>>(Wt, WtT, 768, 0);
  transpose_f2b<<<dim3(24, 24),   256, 0, stream>>>(Wg, WgTT, 768, 0);
  transpose_f2b<<<dim3(24, 24),   256, 0, stream>>>(Wg, WgBT, 768, 768);
  if (bigws)
    transpose_f2b<<<dim3(1572, 24), 256, 0, stream>>>(Wl, WlT, 50257, 0);

  embed_kernel<<<1024, 256, 0, stream>>>(tok, emb, emb_all);
  gbias_kernel<<<3, 256, 0, stream>>>(c2, Wg, gbias);

  // fused-weight + per-token precompute GEMMs (bf16 MFMA, fp32 out)
  launch_gemm(Rw,      V0T,  RV0,   nullptr, 768,  3072, 0, stream);
  launch_gemm(Rw,      WtT,  RWt,   nullptr, 768,  768,  0, stream);
  launch_gemm(W2,      WgBT, W2G,   nullptr, 768,  768,  0, stream);
  launch_gemm(emb_all, V0T,  embV0, b0,      1024, 3072, 0, stream);
  launch_gemm(emb_all, WgTT, embWg, bg,      1024, 768,  0, stream);

  // the sequential part
  recur_kernel<<<256, 256, 0, stream>>>(
      RV0, RWt, W1, W2, W2G, V1, embV0, embWg, gbias, emb_all,
      b1, c1, c2, gamma, beta, h_all,
      a1_if, tg_if, u_if, pre_if, flg);

  // deferred lm_head: logits[b*256+t][v] = h_all @ Wl
  if (bigws) launch_gemm(h_all, WlT, outf, nullptr, 1024, 50257, 0, stream);
  else       launch_gemm(h_all, Wl,  outf, nullptr, 1024, 50257, 1, stream);
}